// Round 4
// baseline (6507.674 us; speedup 1.0000x reference)
//
#include <hip/hip_runtime.h>
#include <math.h>

#define RR 512
#define BB 16
#define TT 64
#define KC 2
#define NN 256

__device__ __forceinline__ float sigmoidf_(float x) {
    return 1.0f / (1.0f + expf(-x));
}

__device__ __forceinline__ float wave_sum(float v) {
    #pragma unroll
    for (int off = 32; off > 0; off >>= 1) v += __shfl_xor(v, off, 64);
    return v;
}
__device__ __forceinline__ float wave_max(float v) {
    #pragma unroll
    for (int off = 32; off > 0; off >>= 1) v = fmaxf(v, __shfl_xor(v, off, 64));
    return v;
}

struct f8 { float4 a, b; };
__device__ __forceinline__ f8 ld8(const float* p) {
    f8 r; r.a = ((const float4*)p)[0]; r.b = ((const float4*)p)[1]; return r;
}
__device__ __forceinline__ void st8(float* p, const f8& v) {
    ((float4*)p)[0] = v.a; ((float4*)p)[1] = v.b;
}
__device__ __forceinline__ float dot8(const f8& x, const f8& y) {
    return x.a.x*y.a.x + x.a.y*y.a.y + x.a.z*y.a.z + x.a.w*y.a.w
         + x.b.x*y.b.x + x.b.y*y.b.y + x.b.z*y.b.z + x.b.w*y.b.w;
}
// inline function, NOT a macro (macro param `w` collides with float4::w)
__device__ __forceinline__ void upd8(f8& m, const f8& u, float zf) {
    m.a.x = zf * (m.a.x + u.a.x); m.a.y = zf * (m.a.y + u.a.y);
    m.a.z = zf * (m.a.z + u.a.z); m.a.w = zf * (m.a.w + u.a.w);
    m.b.x = zf * (m.b.x + u.b.x); m.b.y = zf * (m.b.y + u.b.y);
    m.b.z = zf * (m.b.z + u.b.z); m.b.w = zf * (m.b.w + u.b.w);
}
// acc = acc*sc + wgt*m
__device__ __forceinline__ void fmaacc8(f8& acc, float sc, const f8& m, float wgt) {
    acc.a.x = acc.a.x*sc + wgt*m.a.x; acc.a.y = acc.a.y*sc + wgt*m.a.y;
    acc.a.z = acc.a.z*sc + wgt*m.a.z; acc.a.w = acc.a.w*sc + wgt*m.a.w;
    acc.b.x = acc.b.x*sc + wgt*m.b.x; acc.b.y = acc.b.y*sc + wgt*m.b.y;
    acc.b.z = acc.b.z*sc + wgt*m.b.z; acc.b.w = acc.b.w*sc + wgt*m.b.w;
}

// Payload-halving reduction: p[0..15] partial sums per b across 64 lanes.
// Returns: each lane holds the full sum for b = (lane>>2)&15.
__device__ __forceinline__ float reduce16(float* p, int lane) {
    float q[8];
    {
        bool hi = (lane & 32) != 0;
        #pragma unroll
        for (int i = 0; i < 8; ++i) {
            float snd = hi ? p[i] : p[i + 8];
            float r = __shfl_xor(snd, 32, 64);
            q[i] = (hi ? p[i + 8] : p[i]) + r;
        }
    }
    float s4[4];
    {
        bool hi = (lane & 16) != 0;
        #pragma unroll
        for (int i = 0; i < 4; ++i) {
            float snd = hi ? q[i] : q[i + 4];
            float r = __shfl_xor(snd, 16, 64);
            s4[i] = (hi ? q[i + 4] : q[i]) + r;
        }
    }
    float d2[2];
    {
        bool hi = (lane & 8) != 0;
        #pragma unroll
        for (int i = 0; i < 2; ++i) {
            float snd = hi ? s4[i] : s4[i + 2];
            float r = __shfl_xor(snd, 8, 64);
            d2[i] = (hi ? s4[i + 2] : s4[i]) + r;
        }
    }
    float v;
    {
        bool hi = (lane & 4) != 0;
        float snd = hi ? d2[0] : d2[1];
        float r = __shfl_xor(snd, 4, 64);
        v = (hi ? d2[1] : d2[0]) + r;
    }
    v += __shfl_xor(v, 2, 64);
    v += __shfl_xor(v, 1, 64);
    return v;
}

__device__ __forceinline__ float gatedot(const f8* A, const float* Wrow, int lane) {
    f8 w = ld8(Wrow + lane * 8);
    float p[16];
    #pragma unroll
    for (int b = 0; b < 16; ++b) p[b] = dot8(A[b], w);
    return reduce16(p, lane);
}
__device__ __forceinline__ void ldact(f8* A, const float* act, int lane) {
    #pragma unroll
    for (int b = 0; b < 16; ++b) A[b] = ld8(act + b * 512 + lane * 8);
}

// ---------------------------------------------------------------------------
// k_pre: pre[t*16+b][j] = [emb|io] @ Wih_r^T + bih_r + bhh_r   (proven r1)
// ---------------------------------------------------------------------------
__global__ void k_pre(const float* __restrict__ emb, const float* __restrict__ io,
                      const float* __restrict__ Wih, const float* __restrict__ bih,
                      const float* __restrict__ bhh, float* __restrict__ pre)
{
    __shared__ float As[16][65];
    __shared__ float Bs[16][65];
    int tid = threadIdx.x;
    int row0 = blockIdx.y * 64;
    int col0 = blockIdx.x * 64;
    int ty = tid >> 4, tx = tid & 15;
    float acc[4][4] = {};
    int lr = tid >> 2;
    int lk4 = (tid & 3) * 4;
    for (int k0 = 0; k0 < 1024; k0 += 16) {
        int grow = row0 + lr;
        int b = grow & 15;
        #pragma unroll
        for (int q = 0; q < 4; ++q) {
            int k = k0 + lk4 + q;
            float v = (k < RR) ? emb[(size_t)grow * RR + k]
                               : io[(size_t)b * RR + (k - RR)];
            As[lk4 + q][lr] = v;
        }
        #pragma unroll
        for (int q = 0; q < 4; ++q) {
            int k = k0 + lk4 + q;
            Bs[lk4 + q][lr] = Wih[(size_t)(col0 + lr) * 1024 + k];
        }
        __syncthreads();
        #pragma unroll
        for (int kk = 0; kk < 16; ++kk) {
            float a[4], bbv[4];
            #pragma unroll
            for (int i = 0; i < 4; ++i) a[i] = As[kk][ty * 4 + i];
            #pragma unroll
            for (int j = 0; j < 4; ++j) bbv[j] = Bs[kk][tx * 4 + j];
            #pragma unroll
            for (int i = 0; i < 4; ++i)
                #pragma unroll
                for (int j = 0; j < 4; ++j)
                    acc[i][j] += a[i] * bbv[j];
        }
        __syncthreads();
    }
    #pragma unroll
    for (int i = 0; i < 4; ++i) {
        int grow = row0 + ty * 4 + i;
        #pragma unroll
        for (int j = 0; j < 4; ++j) {
            int gcol = col0 + tx * 4 + j;
            pre[(size_t)grow * 2048 + gcol] = acc[i][j] + bih[gcol] + bhh[gcol];
        }
    }
}

// ---------------------------------------------------------------------------
// k_upd_sim: deferred M update (z_{t-1},hw_{t-1}) + sim_t + per-block
// online-softmax partial m accumulation (M row reused from registers).
// grid 256 blocks x 256 thr; block bid owns rows bid*32..+32 (kb = bid>>3).
// ---------------------------------------------------------------------------
__global__ void k_upd_sim(float* __restrict__ Mw,
                          const float* __restrict__ hr,
                          const float* __restrict__ hwp,
                          const float* __restrict__ zp,
                          float* __restrict__ simbuf,
                          float* __restrict__ mpart,
                          float* __restrict__ mxpart,
                          int first)
{
    __shared__ float smx4[4];
    __shared__ float smacc[4][512];
    int tid = threadIdx.x, wv = tid >> 6, lane = tid & 63;
    int bid = blockIdx.x;
    int kb = bid >> 3;
    int b = kb & 15;
    int row0 = bid * 32 + wv * 8;
    f8 h = ld8(hr + (size_t)b * 512 + lane * 8);
    f8 w8 = {};
    if (!first) w8 = ld8(hwp + (size_t)b * 512 + lane * 8);
    float mx = -3.0e38f;
    f8 macc = {};
    #pragma unroll
    for (int ii = 0; ii < 8; ++ii) {
        int row = row0 + ii;
        float* rp = Mw + (size_t)row * 512 + lane * 8;
        f8 m = ld8(rp);
        if (!first) {
            float zf = 1.0f - zp[row];
            upd8(m, w8, zf);
            st8(rp, m);
        }
        float s = wave_sum(dot8(m, h));
        if (lane == 0) simbuf[row] = s;
        float nmx = fmaxf(mx, s);
        float sc = expf(mx - nmx);     // first iter: exp(-huge)=0, macc=0
        float wgt = expf(s - nmx);
        fmaacc8(macc, sc, m, wgt);
        mx = nmx;
    }
    if (lane == 0) smx4[wv] = mx;
    __syncthreads();
    float MXb = fmaxf(fmaxf(smx4[0], smx4[1]), fmaxf(smx4[2], smx4[3]));
    float sc2 = expf(mx - MXb);
    float* dst = &smacc[wv][lane * 8];
    dst[0] = macc.a.x * sc2; dst[1] = macc.a.y * sc2;
    dst[2] = macc.a.z * sc2; dst[3] = macc.a.w * sc2;
    dst[4] = macc.b.x * sc2; dst[5] = macc.b.y * sc2;
    dst[6] = macc.b.z * sc2; dst[7] = macc.b.w * sc2;
    __syncthreads();
    for (int r = tid; r < 512; r += 256)
        mpart[(size_t)bid * 512 + r] =
            smacc[0][r] + smacc[1][r] + smacc[2][r] + smacc[3][r];
    if (tid == 0) mxpart[bid] = MXb;
}

// ---------------------------------------------------------------------------
// k_comb: z_t = softmax(sim[kb]); m[kb] = sum_w exp(mx_w - MX)/SUM * mpart_w.
// grid 32 blocks (one per kb) x 256 thr.
// ---------------------------------------------------------------------------
__global__ void k_comb(const float* __restrict__ simbuf,
                       const float* __restrict__ mpart,
                       const float* __restrict__ mxpart,
                       float* __restrict__ zbuf,
                       float* __restrict__ mbuf)
{
    __shared__ float red[8];
    __shared__ float cw8[8];
    int tid = threadIdx.x;
    int kb = blockIdx.x;
    float s = simbuf[kb * 256 + tid];
    float mx = wave_max(s);
    if ((tid & 63) == 0) red[tid >> 6] = mx;
    __syncthreads();
    mx = fmaxf(fmaxf(red[0], red[1]), fmaxf(red[2], red[3]));
    float e = expf(s - mx);
    float sm = wave_sum(e);
    if ((tid & 63) == 0) red[4 + (tid >> 6)] = sm;
    __syncthreads();
    sm = red[4] + red[5] + red[6] + red[7];
    float inv = 1.0f / sm;
    zbuf[kb * 256 + tid] = e * inv;
    if (tid < 8) cw8[tid] = expf(mxpart[kb * 8 + tid] - mx) * inv;
    __syncthreads();
    for (int r = tid; r < 512; r += 256) {
        float acc = 0.f;
        #pragma unroll
        for (int w = 0; w < 8; ++w)
            acc += cw8[w] * mpart[(size_t)(kb * 8 + w) * 512 + r];
        mbuf[(size_t)kb * 512 + r] = acc;
    }
}

// ---------------------------------------------------------------------------
// k_comp: comppre[b][j] = [hr|m0|m1].Wc[j] + bc[j].  grid 128 x 256.
// ---------------------------------------------------------------------------
__global__ void k_comp(const float* __restrict__ hr,
                       const float* __restrict__ mbuf,
                       const float* __restrict__ Wc,
                       const float* __restrict__ bc,
                       float* __restrict__ comppre)
{
    int tid = threadIdx.x, wv = tid >> 6, lane = tid & 63;
    int j = blockIdx.x * 4 + wv;
    float pp[16];
    f8 A[16];
    ldact(A, hr, lane);
    f8 w8 = ld8(Wc + (size_t)j * 1536 + lane * 8);
    #pragma unroll
    for (int b = 0; b < 16; ++b) pp[b] = dot8(A[b], w8);
    ldact(A, mbuf, lane);
    w8 = ld8(Wc + (size_t)j * 1536 + 512 + lane * 8);
    #pragma unroll
    for (int b = 0; b < 16; ++b) pp[b] += dot8(A[b], w8);
    ldact(A, mbuf + 16 * 512, lane);
    w8 = ld8(Wc + (size_t)j * 1536 + 1024 + lane * 8);
    #pragma unroll
    for (int b = 0; b < 16; ++b) pp[b] += dot8(A[b], w8);
    float v = reduce16(pp, lane);
    if ((lane & 3) == 0) {
        int b = (lane >> 2) & 15;
        comppre[b * 512 + j] = v + bc[j];
    }
}

// ---------------------------------------------------------------------------
// k_wr: fused write-LSTM(t) [blocks 0..255] and read-LSTM(t+1) [blocks 256..511].
// t = -1: prologue (read-LSTM(0) only).  t = 63: write half only.
// ---------------------------------------------------------------------------
__global__ void k_wr(const float* __restrict__ comppre,
                     const float* __restrict__ Wih_w,
                     const float* __restrict__ Whh_w,
                     const float* __restrict__ bih_w,
                     const float* __restrict__ bhh_w,
                     const float* __restrict__ hw_in, float* __restrict__ hw_out,
                     const float* __restrict__ cw_in, float* __restrict__ cwS,
                     const float* __restrict__ pre,
                     const float* __restrict__ Whh_r,
                     const float* __restrict__ hr_in, float* __restrict__ hr_out,
                     const float* __restrict__ cr_in, float* __restrict__ crS,
                     float* __restrict__ outputs, int t)
{
    __shared__ float gsm[2][4][16];
    __shared__ float smx[16], sinv[16];
    int tid = threadIdx.x, wv = tid >> 6, lane = tid & 63;

    if (blockIdx.x < 256) {
        if (t < 0) return;
        int u0 = blockIdx.x * 2;
        {
            int b = tid >> 4, g16 = tid & 15;
            float mx = -1e30f;
            for (int i = g16; i < 512; i += 16)
                mx = fmaxf(mx, comppre[b * 512 + i]);
            #pragma unroll
            for (int d = 1; d < 16; d <<= 1) mx = fmaxf(mx, __shfl_xor(mx, d, 64));
            if (g16 == 0) smx[b] = mx;
            __syncthreads();
            float mxb = smx[b];
            float ssum = 0.f;
            for (int i = g16; i < 512; i += 16)
                ssum += expf(comppre[b * 512 + i] - mxb);
            #pragma unroll
            for (int d = 1; d < 16; d <<= 1) ssum += __shfl_xor(ssum, d, 64);
            if (g16 == 0) sinv[b] = 1.0f / ssum;
            __syncthreads();
        }
        f8 E[16];
        #pragma unroll
        for (int b2 = 0; b2 < 16; ++b2) {
            f8 v = ld8(comppre + b2 * 512 + lane * 8);
            float m2 = smx[b2];
            E[b2].a.x = expf(v.a.x - m2); E[b2].a.y = expf(v.a.y - m2);
            E[b2].a.z = expf(v.a.z - m2); E[b2].a.w = expf(v.a.w - m2);
            E[b2].b.x = expf(v.b.x - m2); E[b2].b.y = expf(v.b.y - m2);
            E[b2].b.z = expf(v.b.z - m2); E[b2].b.w = expf(v.b.w - m2);
        }
        float tmpih[2];
        #pragma unroll
        for (int uu = 0; uu < 2; ++uu) {
            int j = wv * 512 + u0 + uu;
            tmpih[uu] = gatedot(E, Wih_w + (size_t)j * 512, lane);
        }
        f8 H[16]; ldact(H, hw_in, lane);
        #pragma unroll
        for (int uu = 0; uu < 2; ++uu) {
            int j = wv * 512 + u0 + uu;
            float vh = gatedot(H, Whh_w + (size_t)j * 512, lane);
            if ((lane & 3) == 0) {
                int bb = (lane >> 2) & 15;
                gsm[uu][wv][bb] = tmpih[uu] * sinv[bb] + vh + bih_w[j] + bhh_w[j];
            }
        }
        __syncthreads();
        if (tid < 32) {
            int bb = tid & 15, uu = tid >> 4;
            int u = u0 + uu;
            float gi = sigmoidf_(gsm[uu][0][bb]);
            float gf = sigmoidf_(gsm[uu][1][bb]);
            float gg = tanhf(gsm[uu][2][bb]);
            float go = sigmoidf_(gsm[uu][3][bb]);
            float c = gf * cw_in[bb * 512 + u] + gi * gg;
            cwS[bb * 512 + u] = c;
            float h = go * tanhf(c);
            hw_out[bb * 512 + u] = h;
            outputs[(size_t)t * 8192 + bb * 512 + u] = h;
        }
    } else {
        if (t >= 63) return;
        int rt = t + 1;
        int u0 = (blockIdx.x - 256) * 2;
        f8 A[16]; ldact(A, hr_in, lane);
        float gv[2];
        #pragma unroll
        for (int uu = 0; uu < 2; ++uu) {
            int j = wv * 512 + u0 + uu;
            gv[uu] = gatedot(A, Whh_r + (size_t)j * 512, lane);
        }
        if ((lane & 3) == 0) {
            int b = (lane >> 2) & 15;
            #pragma unroll
            for (int uu = 0; uu < 2; ++uu)
                gsm[uu][wv][b] = gv[uu] +
                    pre[(size_t)(rt * 16 + b) * 2048 + (wv * 512 + u0 + uu)];
        }
        __syncthreads();
        if (tid < 32) {
            int b = tid & 15, uu = tid >> 4;
            int u = u0 + uu;
            float gi = sigmoidf_(gsm[uu][0][b]);
            float gf = sigmoidf_(gsm[uu][1][b]);
            float gg = tanhf(gsm[uu][2][b]);
            float go = sigmoidf_(gsm[uu][3][b]);
            float c = gf * cr_in[b * 512 + u] + gi * gg;
            crS[b * 512 + u] = c;
            hr_out[b * 512 + u] = go * tanhf(c);
        }
    }
}

// ---------------------------------------------------------------------------
// k_final: apply deferred step-63 update (z_63, hw_63).  grid 8192 x 128.
// ---------------------------------------------------------------------------
__global__ void k_final(float* __restrict__ Mw, const float* __restrict__ z,
                        const float* __restrict__ hw)
{
    int row = blockIdx.x;
    int b = (row >> 8) & 15;
    float zf = 1.0f - z[row];
    float4* rp = (float4*)(Mw + (size_t)row * 512) + threadIdx.x;
    const float4* hp = (const float4*)(hw + (size_t)b * 512) + threadIdx.x;
    float4 m = *rp, h = *hp;
    m.x = zf * (m.x + h.x); m.y = zf * (m.y + h.y);
    m.z = zf * (m.z + h.z); m.w = zf * (m.w + h.w);
    *rp = m;
}

extern "C" void kernel_launch(void* const* d_in, const int* in_sizes, int n_in,
                              void* d_out, int out_size, void* d_ws, size_t ws_size,
                              hipStream_t stream) {
    const float* emb   = (const float*)d_in[0];
    const float* hr0   = (const float*)d_in[1];
    const float* cr0   = (const float*)d_in[2];
    const float* hw0   = (const float*)d_in[3];
    const float* cw0   = (const float*)d_in[4];
    const float* io    = (const float*)d_in[5];
    const float* M0    = (const float*)d_in[6];
    const float* Wih_r = (const float*)d_in[7];
    const float* Whh_r = (const float*)d_in[8];
    const float* bih_r = (const float*)d_in[9];
    const float* bhh_r = (const float*)d_in[10];
    const float* Wc    = (const float*)d_in[11];
    const float* bc    = (const float*)d_in[12];
    const float* Wih_w = (const float*)d_in[13];
    const float* Whh_w = (const float*)d_in[14];
    const float* bih_w = (const float*)d_in[15];
    const float* bhh_w = (const float*)d_in[16];

    float* out = (float*)d_out;
    float* outputs = out;                    // [64][16][512]
    float* hrS1 = out + 524288;              // hr slot = hr buffer parity 1
    float* crS  = out + 532480;              // cr (in-place state)
    float* hwS1 = out + 540672;              // hw slot = hw buffer parity 1
    float* cwS  = out + 548864;              // cw (in-place state)
    float* Mw   = out + 557056;              // working M / Mf

    float* ws = (float*)d_ws;
    float* pre     = ws;                     // 1024*2048
    float* simbuf  = ws + 2097152;           // 8192
    float* zbuf    = simbuf + 8192;          // 8192
    float* mbuf    = zbuf + 8192;            // 32*512
    float* comppre = mbuf + 16384;           // 16*512
    float* hrB0    = comppre + 8192;         // 8192 (hr parity 0)
    float* hwB0    = hrB0 + 8192;            // 8192 (hw parity 0)
    float* mpart   = hwB0 + 8192;            // 256*512
    float* mxpart  = mpart + 131072;         // 256

    (void)hipMemcpyAsync(Mw, M0, (size_t)KC * BB * NN * RR * sizeof(float),
                         hipMemcpyDeviceToDevice, stream);

    k_pre<<<dim3(32, 16), 256, 0, stream>>>(emb, io, Wih_r, bih_r, bhh_r, pre);

    // prologue: read-LSTM(0): hr0/cr0 -> hrB0 (parity 0), crS
    k_wr<<<512, 256, 0, stream>>>(comppre, Wih_w, Whh_w, bih_w, bhh_w,
                                  hw0, hwB0, cw0, cwS,
                                  pre, Whh_r, hr0, hrB0, cr0, crS, outputs, -1);

    for (int t = 0; t < TT; ++t) {
        float* hrcur  = (t & 1) ? hrS1 : hrB0;      // hr_t
        float* hrnext = (t & 1) ? hrB0 : hrS1;      // hr_{t+1}
        const float* hwprev = (t == 0) ? hw0 : (((t - 1) & 1) ? hwS1 : hwB0);
        float* hwnext = (t & 1) ? hwS1 : hwB0;      // hw_t
        const float* cwprev = (t == 0) ? cw0 : cwS;

        k_upd_sim<<<256, 256, 0, stream>>>(Mw, hrcur, hwprev, zbuf,
                                           simbuf, mpart, mxpart, t == 0);
        k_comb<<<32, 256, 0, stream>>>(simbuf, mpart, mxpart, zbuf, mbuf);
        k_comp<<<128, 256, 0, stream>>>(hrcur, mbuf, Wc, bc, comppre);
        k_wr<<<512, 256, 0, stream>>>(comppre, Wih_w, Whh_w, bih_w, bhh_w,
                                      hwprev, hwnext, cwprev, cwS,
                                      pre, Whh_r,
                                      hrcur, hrnext, crS, crS, outputs, t);
    }
    // final deferred update with (z_63, hw_63); hw_63 in hwS1 (t=63 odd)
    k_final<<<8192, 128, 0, stream>>>(Mw, zbuf, hwS1);
}

// Round 5
// 6395.079 us; speedup vs baseline: 1.0176x; 1.0176x over previous
//
#include <hip/hip_runtime.h>
#include <math.h>

#define RR 512
#define BB 16
#define TT 64
#define KC 2
#define NN 256
#define NBLK 256

__device__ __forceinline__ float sigmoidf_(float x) {
    return 1.0f / (1.0f + __expf(-x));
}

__device__ __forceinline__ float wave_sum(float v) {
    #pragma unroll
    for (int off = 32; off > 0; off >>= 1) v += __shfl_xor(v, off, 64);
    return v;
}
__device__ __forceinline__ float wave_max(float v) {
    #pragma unroll
    for (int off = 32; off > 0; off >>= 1) v = fmaxf(v, __shfl_xor(v, off, 64));
    return v;
}

struct f8 { float4 a, b; };
__device__ __forceinline__ f8 ld8(const float* p) {
    f8 r; r.a = ((const float4*)p)[0]; r.b = ((const float4*)p)[1]; return r;
}
__device__ __forceinline__ void st8(float* p, const f8& v) {
    ((float4*)p)[0] = v.a; ((float4*)p)[1] = v.b;
}
__device__ __forceinline__ float dot8(const f8& x, const f8& y) {
    return x.a.x*y.a.x + x.a.y*y.a.y + x.a.z*y.a.z + x.a.w*y.a.w
         + x.b.x*y.b.x + x.b.y*y.b.y + x.b.z*y.b.z + x.b.w*y.b.w;
}
// inline function, NOT a macro (macro param `w` collides with float4::w)
__device__ __forceinline__ void upd8(f8& m, const f8& u, float zf) {
    m.a.x = zf * (m.a.x + u.a.x); m.a.y = zf * (m.a.y + u.a.y);
    m.a.z = zf * (m.a.z + u.a.z); m.a.w = zf * (m.a.w + u.a.w);
    m.b.x = zf * (m.b.x + u.b.x); m.b.y = zf * (m.b.y + u.b.y);
    m.b.z = zf * (m.b.z + u.b.z); m.b.w = zf * (m.b.w + u.b.w);
}
__device__ __forceinline__ void fmaacc8(f8& acc, float sc, const f8& m, float wgt) {
    acc.a.x = acc.a.x*sc + wgt*m.a.x; acc.a.y = acc.a.y*sc + wgt*m.a.y;
    acc.a.z = acc.a.z*sc + wgt*m.a.z; acc.a.w = acc.a.w*sc + wgt*m.a.w;
    acc.b.x = acc.b.x*sc + wgt*m.b.x; acc.b.y = acc.b.y*sc + wgt*m.b.y;
    acc.b.z = acc.b.z*sc + wgt*m.b.z; acc.b.w = acc.b.w*sc + wgt*m.b.w;
}

// Payload-halving butterfly: p[0..15] per-b partials across 64 lanes ->
// each lane returns the full sum for b = (lane>>2)&15.
__device__ __forceinline__ float reduce16(float* p, int lane) {
    float q[8];
    {
        bool hi = (lane & 32) != 0;
        #pragma unroll
        for (int i = 0; i < 8; ++i) {
            float snd = hi ? p[i] : p[i + 8];
            float r = __shfl_xor(snd, 32, 64);
            q[i] = (hi ? p[i + 8] : p[i]) + r;
        }
    }
    float s4[4];
    {
        bool hi = (lane & 16) != 0;
        #pragma unroll
        for (int i = 0; i < 4; ++i) {
            float snd = hi ? q[i] : q[i + 4];
            float r = __shfl_xor(snd, 16, 64);
            s4[i] = (hi ? q[i + 4] : q[i]) + r;
        }
    }
    float d2[2];
    {
        bool hi = (lane & 8) != 0;
        #pragma unroll
        for (int i = 0; i < 2; ++i) {
            float snd = hi ? s4[i] : s4[i + 2];
            float r = __shfl_xor(snd, 8, 64);
            d2[i] = (hi ? s4[i + 2] : s4[i]) + r;
        }
    }
    float v;
    {
        bool hi = (lane & 4) != 0;
        float snd = hi ? d2[0] : d2[1];
        float r = __shfl_xor(snd, 4, 64);
        v = (hi ? d2[1] : d2[0]) + r;
    }
    v += __shfl_xor(v, 2, 64);
    v += __shfl_xor(v, 1, 64);
    return v;
}

__device__ __forceinline__ float gatedot(const f8* A, const float* Wrow, int lane) {
    f8 w = ld8(Wrow + lane * 8);
    float p[16];
    #pragma unroll
    for (int b = 0; b < 16; ++b) p[b] = dot8(A[b], w);
    return reduce16(p, lane);
}
__device__ __forceinline__ void ldact(f8* A, const float* act, int lane) {
    #pragma unroll
    for (int b = 0; b < 16; ++b) A[b] = ld8(act + b * 512 + lane * 8);
}

// Software grid barrier: counting + generation spin, agent-scope atomics.
// acq_rel RMW emits the L2 writeback / invalidate needed for cross-XCD
// visibility of plain loads/stores (grid.sync() semantics).
__device__ __forceinline__ void gridbar(unsigned* cnt, unsigned* gen, unsigned target) {
    __syncthreads();
    if (threadIdx.x == 0) {
        unsigned arrived = __hip_atomic_fetch_add(cnt, 1u, __ATOMIC_ACQ_REL,
                                                  __HIP_MEMORY_SCOPE_AGENT);
        if (arrived == (unsigned)(NBLK - 1)) {
            __hip_atomic_store(cnt, 0u, __ATOMIC_RELAXED, __HIP_MEMORY_SCOPE_AGENT);
            __hip_atomic_store(gen, target, __ATOMIC_RELEASE, __HIP_MEMORY_SCOPE_AGENT);
        } else {
            while (__hip_atomic_load(gen, __ATOMIC_RELAXED,
                                     __HIP_MEMORY_SCOPE_AGENT) < target) {
                __builtin_amdgcn_s_sleep(1);
            }
            (void)__hip_atomic_load(gen, __ATOMIC_ACQUIRE, __HIP_MEMORY_SCOPE_AGENT);
        }
    }
    __syncthreads();
}

// ---------------------------------------------------------------------------
// k_pre: pre[t*16+b][j] = [emb|io] @ Wih_r^T + bih_r + bhh_r   (proven r1/r4)
// ---------------------------------------------------------------------------
__global__ void k_pre(const float* __restrict__ emb, const float* __restrict__ io,
                      const float* __restrict__ Wih, const float* __restrict__ bih,
                      const float* __restrict__ bhh, float* __restrict__ pre)
{
    __shared__ float As[16][65];
    __shared__ float Bs[16][65];
    int tid = threadIdx.x;
    int row0 = blockIdx.y * 64;
    int col0 = blockIdx.x * 64;
    int ty = tid >> 4, tx = tid & 15;
    float acc[4][4] = {};
    int lr = tid >> 2;
    int lk4 = (tid & 3) * 4;
    for (int k0 = 0; k0 < 1024; k0 += 16) {
        int grow = row0 + lr;
        int b = grow & 15;
        #pragma unroll
        for (int q = 0; q < 4; ++q) {
            int k = k0 + lk4 + q;
            float v = (k < RR) ? emb[(size_t)grow * RR + k]
                               : io[(size_t)b * RR + (k - RR)];
            As[lk4 + q][lr] = v;
        }
        #pragma unroll
        for (int q = 0; q < 4; ++q) {
            int k = k0 + lk4 + q;
            Bs[lk4 + q][lr] = Wih[(size_t)(col0 + lr) * 1024 + k];
        }
        __syncthreads();
        #pragma unroll
        for (int kk = 0; kk < 16; ++kk) {
            float a[4], bbv[4];
            #pragma unroll
            for (int i = 0; i < 4; ++i) a[i] = As[kk][ty * 4 + i];
            #pragma unroll
            for (int j = 0; j < 4; ++j) bbv[j] = Bs[kk][tx * 4 + j];
            #pragma unroll
            for (int i = 0; i < 4; ++i)
                #pragma unroll
                for (int j = 0; j < 4; ++j)
                    acc[i][j] += a[i] * bbv[j];
        }
        __syncthreads();
    }
    #pragma unroll
    for (int i = 0; i < 4; ++i) {
        int grow = row0 + ty * 4 + i;
        #pragma unroll
        for (int j = 0; j < 4; ++j) {
            int gcol = col0 + tx * 4 + j;
            pre[(size_t)grow * 2048 + gcol] = acc[i][j] + bih[gcol] + bhh[gcol];
        }
    }
}

struct P {
    const float *pre, *Whh_r, *Wc, *bc, *Wih_w, *Whh_w, *bih_w, *bhh_w;
    const float *hr0, *cr0, *hw0, *cw0;
    float *simbuf, *zbuf, *mbuf, *comppre, *mpart, *mxpart;
    float *hrb0, *hrb1, *crS, *hwb0, *hwb1, *cwS;
    float *outputs, *Mw;
    unsigned *cnt, *gen;
};

// ---------------------------------------------------------------------------
// Persistent kernel: 64-step recurrence, software grid barriers.
// 256 blocks x 256 threads (1 block/CU -> co-resident).
// ---------------------------------------------------------------------------
__global__ void __launch_bounds__(256, 1) k_persist(P p)
{
    const int tid = threadIdx.x;
    const int bid = blockIdx.x;
    const int wv = tid >> 6;
    const int lane = tid & 63;
    const int u0 = bid * 2;          // this block's 2 u-columns for LSTM stages

    __shared__ float smacc[4][512];  // 8 KB: stage-A online-m per-wave partials
    __shared__ float smx4[4];
    __shared__ float gsm[2][4][16];  // [uu][gate][b]
    __shared__ float cc[2][2][16];   // stage-C partial combine [jj][part][b]
    __shared__ float smx[16], sinv[16];
    __shared__ float red[8];
    __shared__ float cw8[8];

    unsigned tgt = 0;

    // ---- prologue: read-LSTM step 0 -> hr_0 (hrb0), c_0 (crS)
    {
        f8 A[16]; ldact(A, p.hr0, lane);
        int j0 = wv * 512 + u0;
        float gv0 = gatedot(A, p.Whh_r + (size_t)j0 * 512, lane);
        float gv1 = gatedot(A, p.Whh_r + (size_t)(j0 + 1) * 512, lane);
        if ((lane & 3) == 0) {
            int b = (lane >> 2) & 15;
            gsm[0][wv][b] = gv0 + p.pre[(size_t)b * 2048 + j0];
            gsm[1][wv][b] = gv1 + p.pre[(size_t)b * 2048 + j0 + 1];
        }
        __syncthreads();
        if (tid < 32) {
            int b = tid & 15, uu = tid >> 4;
            int u = u0 + uu;
            float gi = sigmoidf_(gsm[uu][0][b]);
            float gf = sigmoidf_(gsm[uu][1][b]);
            float gg = tanhf(gsm[uu][2][b]);
            float go = sigmoidf_(gsm[uu][3][b]);
            float c = gf * p.cr0[b * 512 + u] + gi * gg;
            p.crS[b * 512 + u] = c;
            p.hrb0[b * 512 + u] = go * tanhf(c);
        }
        gridbar(p.cnt, p.gen, ++tgt);
    }

    for (int t = 0; t < TT; ++t) {
        const float* hrcur  = (t & 1) ? p.hrb1 : p.hrb0;   // hr_t
        float*       hrnext = (t & 1) ? p.hrb0 : p.hrb1;   // hr_{t+1}
        const float* hwprev = (t == 0) ? p.hw0 : (((t - 1) & 1) ? p.hwb1 : p.hwb0);
        float*       hwnext = (t & 1) ? p.hwb1 : p.hwb0;   // hw_t

        // ========= stage A: deferred M update + sim + online-m partials
        {
            int wgl = bid * 4 + wv;
            int row0 = wgl * 8;
            int kb = row0 >> 8;
            int b = kb & 15;
            f8 h = ld8(hrcur + (size_t)b * 512 + lane * 8);
            f8 w8 = {};
            if (t > 0) w8 = ld8(hwprev + (size_t)b * 512 + lane * 8);
            float mx = -3.0e38f;
            f8 macc = {};
            #pragma unroll
            for (int ii = 0; ii < 8; ++ii) {
                int row = row0 + ii;
                float* rp = p.Mw + (size_t)row * 512 + lane * 8;
                f8 m = ld8(rp);
                if (t > 0) {
                    float zf = 1.0f - p.zbuf[row];
                    upd8(m, w8, zf);
                    st8(rp, m);
                }
                float s = wave_sum(dot8(m, h));
                if (lane == 0) p.simbuf[row] = s;
                float nmx = fmaxf(mx, s);
                float sc = __expf(mx - nmx);     // first iter: exp(-inf)=0
                float wgt = __expf(s - nmx);
                fmaacc8(macc, sc, m, wgt);
                mx = nmx;
            }
            if (lane == 0) smx4[wv] = mx;
            __syncthreads();
            float MXb = fmaxf(fmaxf(smx4[0], smx4[1]), fmaxf(smx4[2], smx4[3]));
            float sc2 = __expf(mx - MXb);
            float* dst = &smacc[wv][lane * 8];
            dst[0] = macc.a.x * sc2; dst[1] = macc.a.y * sc2;
            dst[2] = macc.a.z * sc2; dst[3] = macc.a.w * sc2;
            dst[4] = macc.b.x * sc2; dst[5] = macc.b.y * sc2;
            dst[6] = macc.b.z * sc2; dst[7] = macc.b.w * sc2;
            __syncthreads();
            for (int r = tid; r < 512; r += 256)
                p.mpart[(size_t)bid * 512 + r] =
                    smacc[0][r] + smacc[1][r] + smacc[2][r] + smacc[3][r];
            if (tid == 0) p.mxpart[bid] = MXb;
        }
        // ========= stage A2: read-LSTM gates for t+1
        if (t < 63) {
            f8 A[16]; ldact(A, hrcur, lane);
            int j0 = wv * 512 + u0;
            float gv0 = gatedot(A, p.Whh_r + (size_t)j0 * 512, lane);
            float gv1 = gatedot(A, p.Whh_r + (size_t)(j0 + 1) * 512, lane);
            if ((lane & 3) == 0) {
                int b = (lane >> 2) & 15;
                gsm[0][wv][b] = gv0 + p.pre[(size_t)((t + 1) * 16 + b) * 2048 + j0];
                gsm[1][wv][b] = gv1 + p.pre[(size_t)((t + 1) * 16 + b) * 2048 + j0 + 1];
            }
            __syncthreads();
            if (tid < 32) {
                int b = tid & 15, uu = tid >> 4;
                int u = u0 + uu;
                float gi = sigmoidf_(gsm[uu][0][b]);
                float gf = sigmoidf_(gsm[uu][1][b]);
                float gg = tanhf(gsm[uu][2][b]);
                float go = sigmoidf_(gsm[uu][3][b]);
                float c = gf * p.crS[b * 512 + u] + gi * gg;
                p.crS[b * 512 + u] = c;
                hrnext[b * 512 + u] = go * tanhf(c);
            }
        }
        gridbar(p.cnt, p.gen, ++tgt);

        // ========= stage B: z = softmax(sim); m = weighted combine of partials
        if (bid < 32) {
            int kb = bid;
            float s = p.simbuf[kb * 256 + tid];
            float mxv = wave_max(s);
            if ((tid & 63) == 0) red[tid >> 6] = mxv;
            __syncthreads();
            mxv = fmaxf(fmaxf(red[0], red[1]), fmaxf(red[2], red[3]));
            float e = __expf(s - mxv);
            float sm = wave_sum(e);
            if ((tid & 63) == 0) red[4 + (tid >> 6)] = sm;
            __syncthreads();
            sm = red[4] + red[5] + red[6] + red[7];
            float inv = 1.0f / sm;
            p.zbuf[kb * 256 + tid] = e * inv;
            if (tid < 8) cw8[tid] = __expf(p.mxpart[kb * 8 + tid] - mxv) * inv;
            __syncthreads();
            for (int r = tid; r < 512; r += 256) {
                float acc = 0.f;
                #pragma unroll
                for (int w2 = 0; w2 < 8; ++w2)
                    acc += cw8[w2] * p.mpart[(size_t)(kb * 8 + w2) * 512 + r];
                p.mbuf[(size_t)kb * 512 + r] = acc;
            }
        }
        gridbar(p.cnt, p.gen, ++tgt);

        // ========= stage C: comppre GEMV (all blocks, 2 j each, waves split
        // the 1536-dot) + hoisted vh = hw_prev . Whh_w (overlaps C window)
        float vh0, vh1;
        {
            f8 H[16]; ldact(H, hwprev, lane);
            int j0 = wv * 512 + u0;
            vh0 = gatedot(H, p.Whh_w + (size_t)j0 * 512, lane);
            vh1 = gatedot(H, p.Whh_w + (size_t)(j0 + 1) * 512, lane);
        }
        {
            int jj = wv >> 1;
            int part = wv & 1;
            int j = bid * 2 + jj;
            float v;
            f8 A[16];
            if (part == 0) {
                ldact(A, hrcur, lane);
                v = gatedot(A, p.Wc + (size_t)j * 1536, lane);
                ldact(A, p.mbuf, lane);
                v += gatedot(A, p.Wc + (size_t)j * 1536 + 512, lane);
            } else {
                ldact(A, p.mbuf + 16 * 512, lane);
                v = gatedot(A, p.Wc + (size_t)j * 1536 + 1024, lane);
            }
            if ((lane & 3) == 0) {
                int b = (lane >> 2) & 15;
                cc[jj][part][b] = v;
            }
            __syncthreads();
            if (tid < 32) {
                int b = tid & 15, jj2 = tid >> 4;
                int j2 = bid * 2 + jj2;
                p.comppre[b * 512 + j2] = cc[jj2][0][b] + cc[jj2][1][b] + p.bc[j2];
            }
        }
        gridbar(p.cnt, p.gen, ++tgt);

        // ========= stage D: softmax(comppre) folded into write-LSTM
        {
            int b = tid >> 4, g16 = tid & 15;
            float mxs = -1e30f;
            for (int i = g16; i < 512; i += 16)
                mxs = fmaxf(mxs, p.comppre[b * 512 + i]);
            #pragma unroll
            for (int d = 1; d < 16; d <<= 1) mxs = fmaxf(mxs, __shfl_xor(mxs, d, 64));
            if (g16 == 0) smx[b] = mxs;
            __syncthreads();
            float mxb = smx[b];
            float ssum = 0.f;
            for (int i = g16; i < 512; i += 16)
                ssum += __expf(p.comppre[b * 512 + i] - mxb);
            #pragma unroll
            for (int d = 1; d < 16; d <<= 1) ssum += __shfl_xor(ssum, d, 64);
            if (g16 == 0) sinv[b] = 1.0f / ssum;
            __syncthreads();

            f8 E[16];
            #pragma unroll
            for (int b2 = 0; b2 < 16; ++b2) {
                f8 v = ld8(p.comppre + b2 * 512 + lane * 8);
                float m2 = smx[b2];
                E[b2].a.x = __expf(v.a.x - m2); E[b2].a.y = __expf(v.a.y - m2);
                E[b2].a.z = __expf(v.a.z - m2); E[b2].a.w = __expf(v.a.w - m2);
                E[b2].b.x = __expf(v.b.x - m2); E[b2].b.y = __expf(v.b.y - m2);
                E[b2].b.z = __expf(v.b.z - m2); E[b2].b.w = __expf(v.b.w - m2);
            }
            int j0 = wv * 512 + u0;
            float ti0 = gatedot(E, p.Wih_w + (size_t)j0 * 512, lane);
            float ti1 = gatedot(E, p.Wih_w + (size_t)(j0 + 1) * 512, lane);
            if ((lane & 3) == 0) {
                int bb = (lane >> 2) & 15;
                gsm[0][wv][bb] = ti0 * sinv[bb] + vh0 + p.bih_w[j0] + p.bhh_w[j0];
                gsm[1][wv][bb] = ti1 * sinv[bb] + vh1 + p.bih_w[j0 + 1] + p.bhh_w[j0 + 1];
            }
            __syncthreads();
            if (tid < 32) {
                int bb = tid & 15, uu = tid >> 4;
                int u = u0 + uu;
                float gi = sigmoidf_(gsm[uu][0][bb]);
                float gf = sigmoidf_(gsm[uu][1][bb]);
                float gg = tanhf(gsm[uu][2][bb]);
                float go = sigmoidf_(gsm[uu][3][bb]);
                float cprev = (t == 0) ? p.cw0[bb * 512 + u] : p.cwS[bb * 512 + u];
                float c = gf * cprev + gi * gg;
                p.cwS[bb * 512 + u] = c;
                float h = go * tanhf(c);
                hwnext[bb * 512 + u] = h;
                p.outputs[(size_t)t * 8192 + bb * 512 + u] = h;
            }
        }
        gridbar(p.cnt, p.gen, ++tgt);
    }

    // ---- epilogue: final deferred M update with (z_63, hw_63 = hwb1)
    {
        int wgl = bid * 4 + wv;
        int row0 = wgl * 8;
        int b = (row0 >> 8) & 15;
        f8 w8 = ld8(p.hwb1 + (size_t)b * 512 + lane * 8);
        #pragma unroll
        for (int ii = 0; ii < 8; ++ii) {
            int row = row0 + ii;
            float zf = 1.0f - p.zbuf[row];
            float* rp = p.Mw + (size_t)row * 512 + lane * 8;
            f8 m = ld8(rp);
            upd8(m, w8, zf);
            st8(rp, m);
        }
    }
    // hr_63 already in hrb1 (= d_out hr slot), hw_63 in hwb1 (= d_out hw slot),
    // cr/cw updated in place in d_out. Kernel-end flush publishes everything.
}

extern "C" void kernel_launch(void* const* d_in, const int* in_sizes, int n_in,
                              void* d_out, int out_size, void* d_ws, size_t ws_size,
                              hipStream_t stream) {
    const float* emb   = (const float*)d_in[0];
    const float* hr0   = (const float*)d_in[1];
    const float* cr0   = (const float*)d_in[2];
    const float* hw0   = (const float*)d_in[3];
    const float* cw0   = (const float*)d_in[4];
    const float* io    = (const float*)d_in[5];
    const float* M0    = (const float*)d_in[6];
    const float* Wih_r = (const float*)d_in[7];
    const float* bih_r = (const float*)d_in[9];
    const float* bhh_r = (const float*)d_in[10];

    float* out = (float*)d_out;
    float* outputs = out;                    // [64][16][512]
    float* hrS1 = out + 524288;              // hr slot doubles as hr parity-1 buf
    float* crS  = out + 532480;              // cr (in-place state)
    float* hwS1 = out + 540672;              // hw slot doubles as hw parity-1 buf
    float* cwS  = out + 548864;              // cw (in-place state)
    float* Mw   = out + 557056;              // working M / Mf

    float* ws = (float*)d_ws;
    float* pre     = ws;                     // 1024*2048
    float* simbuf  = ws + 2097152;           // 8192
    float* zbuf    = simbuf + 8192;          // 8192
    float* mbuf    = zbuf + 8192;            // 32*512
    float* comppre = mbuf + 16384;           // 16*512
    float* hrB0    = comppre + 8192;         // 8192 (hr parity 0)
    float* hwB0    = hrB0 + 8192;            // 8192 (hw parity 0)
    float* mpart   = hwB0 + 8192;            // 256*512
    float* mxpart  = mpart + 131072;         // 256
    unsigned* bar  = (unsigned*)(mxpart + 256); // [cnt, gen]

    (void)hipMemsetAsync(bar, 0, 2 * sizeof(unsigned), stream);
    (void)hipMemcpyAsync(Mw, M0, (size_t)KC * BB * NN * RR * sizeof(float),
                         hipMemcpyDeviceToDevice, stream);

    k_pre<<<dim3(32, 16), 256, 0, stream>>>(emb, io, Wih_r, bih_r, bhh_r, pre);

    P p;
    p.pre = pre;
    p.Whh_r = (const float*)d_in[8];
    p.Wc    = (const float*)d_in[11];
    p.bc    = (const float*)d_in[12];
    p.Wih_w = (const float*)d_in[13];
    p.Whh_w = (const float*)d_in[14];
    p.bih_w = (const float*)d_in[15];
    p.bhh_w = (const float*)d_in[16];
    p.hr0 = hr0; p.cr0 = cr0; p.hw0 = hw0; p.cw0 = cw0;
    p.simbuf = simbuf; p.zbuf = zbuf; p.mbuf = mbuf; p.comppre = comppre;
    p.mpart = mpart; p.mxpart = mxpart;
    p.hrb0 = hrB0; p.hrb1 = hrS1; p.crS = crS;
    p.hwb0 = hwB0; p.hwb1 = hwS1; p.cwS = cwS;
    p.outputs = outputs; p.Mw = Mw;
    p.cnt = bar; p.gen = bar + 1;

    k_persist<<<NBLK, 256, 0, stream>>>(p);
}

// Round 6
// 4531.410 us; speedup vs baseline: 1.4361x; 1.4113x over previous
//
#include <hip/hip_runtime.h>
#include <math.h>

#define RR 512
#define BB 16
#define TT 64
#define KC 2
#define NN 256
#define NBLK 256

__device__ __forceinline__ float sigmoidf_(float x) {
    return 1.0f / (1.0f + __expf(-x));
}

__device__ __forceinline__ float wave_sum(float v) {
    #pragma unroll
    for (int off = 32; off > 0; off >>= 1) v += __shfl_xor(v, off, 64);
    return v;
}
__device__ __forceinline__ float wave_max(float v) {
    #pragma unroll
    for (int off = 32; off > 0; off >>= 1) v = fmaxf(v, __shfl_xor(v, off, 64));
    return v;
}

struct f8 { float4 a, b; };
__device__ __forceinline__ f8 ld8(const float* p) {
    f8 r; r.a = ((const float4*)p)[0]; r.b = ((const float4*)p)[1]; return r;
}
// split-slice: thread's 8 floats of a 512-row are [lane*4,+4) and [256+lane*4,+4)
// (16 B/lane contiguous per half-row -> conflict-clean LDS + coalesced global)
__device__ __forceinline__ f8 ld8s(const float* row, int lane) {
    f8 r;
    r.a = *(const float4*)(row + lane * 4);
    r.b = *(const float4*)(row + 256 + lane * 4);
    return r;
}
__device__ __forceinline__ void st8s(float* row, const f8& v, int lane) {
    *(float4*)(row + lane * 4) = v.a;
    *(float4*)(row + 256 + lane * 4) = v.b;
}
__device__ __forceinline__ float dot8(const f8& x, const f8& y) {
    return x.a.x*y.a.x + x.a.y*y.a.y + x.a.z*y.a.z + x.a.w*y.a.w
         + x.b.x*y.b.x + x.b.y*y.b.y + x.b.z*y.b.z + x.b.w*y.b.w;
}
// inline function, NOT a macro (macro param `w` collides with float4::w)
__device__ __forceinline__ void upd8(f8& m, const f8& u, float zf) {
    m.a.x = zf * (m.a.x + u.a.x); m.a.y = zf * (m.a.y + u.a.y);
    m.a.z = zf * (m.a.z + u.a.z); m.a.w = zf * (m.a.w + u.a.w);
    m.b.x = zf * (m.b.x + u.b.x); m.b.y = zf * (m.b.y + u.b.y);
    m.b.z = zf * (m.b.z + u.b.z); m.b.w = zf * (m.b.w + u.b.w);
}
__device__ __forceinline__ void fmaacc8(f8& acc, float sc, const f8& m, float wgt) {
    acc.a.x = acc.a.x*sc + wgt*m.a.x; acc.a.y = acc.a.y*sc + wgt*m.a.y;
    acc.a.z = acc.a.z*sc + wgt*m.a.z; acc.a.w = acc.a.w*sc + wgt*m.a.w;
    acc.b.x = acc.b.x*sc + wgt*m.b.x; acc.b.y = acc.b.y*sc + wgt*m.b.y;
    acc.b.z = acc.b.z*sc + wgt*m.b.z; acc.b.w = acc.b.w*sc + wgt*m.b.w;
}

// Payload-halving butterfly: p[0..15] per-b partials across 64 lanes ->
// each lane returns the full sum for b = (lane>>2)&15.
__device__ __forceinline__ float reduce16(float* p, int lane) {
    float q[8];
    {
        bool hi = (lane & 32) != 0;
        #pragma unroll
        for (int i = 0; i < 8; ++i) {
            float snd = hi ? p[i] : p[i + 8];
            float r = __shfl_xor(snd, 32, 64);
            q[i] = (hi ? p[i + 8] : p[i]) + r;
        }
    }
    float s4[4];
    {
        bool hi = (lane & 16) != 0;
        #pragma unroll
        for (int i = 0; i < 4; ++i) {
            float snd = hi ? q[i] : q[i + 4];
            float r = __shfl_xor(snd, 16, 64);
            s4[i] = (hi ? q[i + 4] : q[i]) + r;
        }
    }
    float d2[2];
    {
        bool hi = (lane & 8) != 0;
        #pragma unroll
        for (int i = 0; i < 2; ++i) {
            float snd = hi ? s4[i] : s4[i + 2];
            float r = __shfl_xor(snd, 8, 64);
            d2[i] = (hi ? s4[i + 2] : s4[i]) + r;
        }
    }
    float v;
    {
        bool hi = (lane & 4) != 0;
        float snd = hi ? d2[0] : d2[1];
        float r = __shfl_xor(snd, 4, 64);
        v = (hi ? d2[1] : d2[0]) + r;
    }
    v += __shfl_xor(v, 2, 64);
    v += __shfl_xor(v, 1, 64);
    return v;
}

__device__ __forceinline__ float gatedot(const f8* A, const float* Wrow, int lane) {
    f8 w = ld8(Wrow + lane * 8);
    float p[16];
    #pragma unroll
    for (int b = 0; b < 16; ++b) p[b] = dot8(A[b], w);
    return reduce16(p, lane);
}
__device__ __forceinline__ void ldact(f8* A, const float* act, int lane) {
    #pragma unroll
    for (int b = 0; b < 16; ++b) A[b] = ld8(act + b * 512 + lane * 8);
}

// Two-level software grid barrier (proven acq_rel protocol from r5, striped to
// cut same-address RMW serialization 256 -> 32 + 8).
// bar layout (uints): grp[i] at i*64 (i<8, own cacheline), master at 512, gen at 576.
__device__ __forceinline__ void gridbar(unsigned* bar, unsigned target) {
    __syncthreads();
    if (threadIdx.x == 0) {
        unsigned* grp    = bar + (blockIdx.x & 7) * 64;   // bid&7 ~ same-XCD group
        unsigned* master = bar + 512;
        unsigned* gen    = bar + 576;
        unsigned a = __hip_atomic_fetch_add(grp, 1u, __ATOMIC_ACQ_REL,
                                            __HIP_MEMORY_SCOPE_AGENT);
        if (a == 31u) {
            __hip_atomic_store(grp, 0u, __ATOMIC_RELAXED, __HIP_MEMORY_SCOPE_AGENT);
            unsigned m = __hip_atomic_fetch_add(master, 1u, __ATOMIC_ACQ_REL,
                                                __HIP_MEMORY_SCOPE_AGENT);
            if (m == 7u) {
                __hip_atomic_store(master, 0u, __ATOMIC_RELAXED, __HIP_MEMORY_SCOPE_AGENT);
                __hip_atomic_store(gen, target, __ATOMIC_RELEASE, __HIP_MEMORY_SCOPE_AGENT);
            }
        }
        while (__hip_atomic_load(gen, __ATOMIC_RELAXED,
                                 __HIP_MEMORY_SCOPE_AGENT) < target) {
            __builtin_amdgcn_s_sleep(1);
        }
        (void)__hip_atomic_load(gen, __ATOMIC_ACQUIRE, __HIP_MEMORY_SCOPE_AGENT);
    }
    __syncthreads();
}

// ---------------------------------------------------------------------------
// k_pre: pre[t*16+b][j] = [emb|io] @ Wih_r^T + bih_r + bhh_r   (proven r1/r4/r5)
// ---------------------------------------------------------------------------
__global__ void k_pre(const float* __restrict__ emb, const float* __restrict__ io,
                      const float* __restrict__ Wih, const float* __restrict__ bih,
                      const float* __restrict__ bhh, float* __restrict__ pre)
{
    __shared__ float As[16][65];
    __shared__ float Bs[16][65];
    int tid = threadIdx.x;
    int row0 = blockIdx.y * 64;
    int col0 = blockIdx.x * 64;
    int ty = tid >> 4, tx = tid & 15;
    float acc[4][4] = {};
    int lr = tid >> 2;
    int lk4 = (tid & 3) * 4;
    for (int k0 = 0; k0 < 1024; k0 += 16) {
        int grow = row0 + lr;
        int b = grow & 15;
        #pragma unroll
        for (int q = 0; q < 4; ++q) {
            int k = k0 + lk4 + q;
            float v = (k < RR) ? emb[(size_t)grow * RR + k]
                               : io[(size_t)b * RR + (k - RR)];
            As[lk4 + q][lr] = v;
        }
        #pragma unroll
        for (int q = 0; q < 4; ++q) {
            int k = k0 + lk4 + q;
            Bs[lk4 + q][lr] = Wih[(size_t)(col0 + lr) * 1024 + k];
        }
        __syncthreads();
        #pragma unroll
        for (int kk = 0; kk < 16; ++kk) {
            float a[4], bbv[4];
            #pragma unroll
            for (int i = 0; i < 4; ++i) a[i] = As[kk][ty * 4 + i];
            #pragma unroll
            for (int j = 0; j < 4; ++j) bbv[j] = Bs[kk][tx * 4 + j];
            #pragma unroll
            for (int i = 0; i < 4; ++i)
                #pragma unroll
                for (int j = 0; j < 4; ++j)
                    acc[i][j] += a[i] * bbv[j];
        }
        __syncthreads();
    }
    #pragma unroll
    for (int i = 0; i < 4; ++i) {
        int grow = row0 + ty * 4 + i;
        #pragma unroll
        for (int j = 0; j < 4; ++j) {
            int gcol = col0 + tx * 4 + j;
            pre[(size_t)grow * 2048 + gcol] = acc[i][j] + bih[gcol] + bhh[gcol];
        }
    }
}

struct P {
    const float *pre, *Whh_r, *Wc, *bc, *Wih_w, *Whh_w, *bih_w, *bhh_w;
    const float *hr0, *cr0, *hw0, *cw0, *M0;
    float *simbuf, *zbuf, *mbuf, *comppre, *mpart, *mxpart;
    float *hrb0, *hrb1, *crS, *hwb0, *hwb1, *cwS;
    float *outputs, *Mw;
    unsigned *bar;
};

// ---------------------------------------------------------------------------
// Persistent kernel: 64-step recurrence; M lives in LDS (block-private rows,
// loaded once, written once) so barriers never flush it through the MALL.
// 256 blocks x 256 threads.
// ---------------------------------------------------------------------------
__global__ void __launch_bounds__(256, 1) k_persist(P p)
{
    const int tid = threadIdx.x;
    const int bid = blockIdx.x;
    const int wv = tid >> 6;
    const int lane = tid & 63;
    const int u0 = bid * 2;          // this block's 2 u-columns for LSTM stages
    const int bM = (bid >> 3) & 15;  // batch index of this block's M rows

    __shared__ float Mlds[32][512];  // 64 KB: this block's 32 M rows, all 64 steps
    __shared__ float smacc[4][512];  // stage-A online-m per-wave partials
    __shared__ float smx4[4];
    __shared__ float gsm[2][4][16];  // [uu][gate][b]
    __shared__ float cc[2][2][16];   // stage-C partial combine [jj][part][b]
    __shared__ float smx[16], sinv[16];
    __shared__ float red[8];
    __shared__ float cw8[8];

    unsigned tgt = 0;

    // ---- load this block's M rows: global M0 -> LDS (once)
    {
        const float4* src = (const float4*)(p.M0 + (size_t)bid * 32 * 512);
        float4* dst = (float4*)&Mlds[0][0];
        #pragma unroll 4
        for (int idx = tid; idx < 32 * 128; idx += 256)
            dst[idx] = src[idx];
    }

    // ---- prologue: read-LSTM step 0 -> hr_0 (hrb0), c_0 (crS)
    {
        f8 A[16]; ldact(A, p.hr0, lane);
        int j0 = wv * 512 + u0;
        float gv0 = gatedot(A, p.Whh_r + (size_t)j0 * 512, lane);
        float gv1 = gatedot(A, p.Whh_r + (size_t)(j0 + 1) * 512, lane);
        if ((lane & 3) == 0) {
            int b = (lane >> 2) & 15;
            gsm[0][wv][b] = gv0 + p.pre[(size_t)b * 2048 + j0];
            gsm[1][wv][b] = gv1 + p.pre[(size_t)b * 2048 + j0 + 1];
        }
        __syncthreads();
        if (tid < 32) {
            int b = tid & 15, uu = tid >> 4;
            int u = u0 + uu;
            float gi = sigmoidf_(gsm[uu][0][b]);
            float gf = sigmoidf_(gsm[uu][1][b]);
            float gg = tanhf(gsm[uu][2][b]);
            float go = sigmoidf_(gsm[uu][3][b]);
            float c = gf * p.cr0[b * 512 + u] + gi * gg;
            p.crS[b * 512 + u] = c;
            p.hrb0[b * 512 + u] = go * tanhf(c);
        }
        gridbar(p.bar, ++tgt);
    }

    for (int t = 0; t < TT; ++t) {
        const float* hrcur  = (t & 1) ? p.hrb1 : p.hrb0;   // hr_t
        float*       hrnext = (t & 1) ? p.hrb0 : p.hrb1;   // hr_{t+1}
        const float* hwprev = (t == 0) ? p.hw0 : (((t - 1) & 1) ? p.hwb1 : p.hwb0);
        float*       hwnext = (t & 1) ? p.hwb1 : p.hwb0;   // hw_t

        // ========= stage A: deferred M update (in LDS) + sim + online-m partials
        {
            f8 h = ld8s(hrcur + (size_t)bM * 512, lane);
            f8 w8 = {};
            if (t > 0) w8 = ld8s(hwprev + (size_t)bM * 512, lane);
            float mx = -3.0e38f;
            f8 macc = {};
            #pragma unroll
            for (int ii = 0; ii < 8; ++ii) {
                int rl = wv * 8 + ii;
                float4* mp0 = (float4*)&Mlds[rl][lane * 4];
                float4* mp1 = (float4*)&Mlds[rl][256 + lane * 4];
                f8 m; m.a = *mp0; m.b = *mp1;
                if (t > 0) {
                    float zf = 1.0f - p.zbuf[bid * 32 + rl];
                    upd8(m, w8, zf);
                    *mp0 = m.a; *mp1 = m.b;
                }
                float s = wave_sum(dot8(m, h));
                if (lane == 0) p.simbuf[bid * 32 + rl] = s;
                float nmx = fmaxf(mx, s);
                float sc = __expf(mx - nmx);     // first iter: exp(-inf)=0
                float wgt = __expf(s - nmx);
                fmaacc8(macc, sc, m, wgt);
                mx = nmx;
            }
            if (lane == 0) smx4[wv] = mx;
            __syncthreads();
            float MXb = fmaxf(fmaxf(smx4[0], smx4[1]), fmaxf(smx4[2], smx4[3]));
            float sc2 = __expf(mx - MXb);
            float* d0 = &smacc[wv][lane * 4];
            float* d1 = &smacc[wv][256 + lane * 4];
            d0[0] = macc.a.x * sc2; d0[1] = macc.a.y * sc2;
            d0[2] = macc.a.z * sc2; d0[3] = macc.a.w * sc2;
            d1[0] = macc.b.x * sc2; d1[1] = macc.b.y * sc2;
            d1[2] = macc.b.z * sc2; d1[3] = macc.b.w * sc2;
            __syncthreads();
            for (int r = tid; r < 512; r += 256)
                p.mpart[(size_t)bid * 512 + r] =
                    smacc[0][r] + smacc[1][r] + smacc[2][r] + smacc[3][r];
            if (tid == 0) p.mxpart[bid] = MXb;
        }
        // ========= stage A2: read-LSTM gates for t+1
        if (t < 63) {
            f8 A[16]; ldact(A, hrcur, lane);
            int j0 = wv * 512 + u0;
            float gv0 = gatedot(A, p.Whh_r + (size_t)j0 * 512, lane);
            float gv1 = gatedot(A, p.Whh_r + (size_t)(j0 + 1) * 512, lane);
            if ((lane & 3) == 0) {
                int b = (lane >> 2) & 15;
                gsm[0][wv][b] = gv0 + p.pre[(size_t)((t + 1) * 16 + b) * 2048 + j0];
                gsm[1][wv][b] = gv1 + p.pre[(size_t)((t + 1) * 16 + b) * 2048 + j0 + 1];
            }
            __syncthreads();
            if (tid < 32) {
                int b = tid & 15, uu = tid >> 4;
                int u = u0 + uu;
                float gi = sigmoidf_(gsm[uu][0][b]);
                float gf = sigmoidf_(gsm[uu][1][b]);
                float gg = tanhf(gsm[uu][2][b]);
                float go = sigmoidf_(gsm[uu][3][b]);
                float c = gf * p.crS[b * 512 + u] + gi * gg;
                p.crS[b * 512 + u] = c;
                hrnext[b * 512 + u] = go * tanhf(c);
            }
        }
        gridbar(p.bar, ++tgt);

        // ========= stage B: z = softmax(sim); m = weighted combine of partials
        if (bid < 32) {
            int kb = bid;
            float s = p.simbuf[kb * 256 + tid];
            float mxv = wave_max(s);
            if ((tid & 63) == 0) red[tid >> 6] = mxv;
            __syncthreads();
            mxv = fmaxf(fmaxf(red[0], red[1]), fmaxf(red[2], red[3]));
            float e = __expf(s - mxv);
            float sm = wave_sum(e);
            if ((tid & 63) == 0) red[4 + (tid >> 6)] = sm;
            __syncthreads();
            sm = red[4] + red[5] + red[6] + red[7];
            float inv = 1.0f / sm;
            p.zbuf[kb * 256 + tid] = e * inv;
            if (tid < 8) cw8[tid] = __expf(p.mxpart[kb * 8 + tid] - mxv) * inv;
            __syncthreads();
            for (int r = tid; r < 512; r += 256) {
                float acc = 0.f;
                #pragma unroll
                for (int w2 = 0; w2 < 8; ++w2)
                    acc += cw8[w2] * p.mpart[(size_t)(kb * 8 + w2) * 512 + r];
                p.mbuf[(size_t)kb * 512 + r] = acc;
            }
        }
        gridbar(p.bar, ++tgt);

        // ========= stage C: comppre GEMV (2 j per block, waves split the
        // 1536-dot) + hoisted vh = hw_prev . Whh_w (overlaps C window)
        float vh0, vh1;
        {
            f8 H[16]; ldact(H, hwprev, lane);
            int j0 = wv * 512 + u0;
            vh0 = gatedot(H, p.Whh_w + (size_t)j0 * 512, lane);
            vh1 = gatedot(H, p.Whh_w + (size_t)(j0 + 1) * 512, lane);
        }
        {
            int jj = wv >> 1;
            int part = wv & 1;
            int j = bid * 2 + jj;
            float v;
            f8 A[16];
            if (part == 0) {
                ldact(A, hrcur, lane);
                v = gatedot(A, p.Wc + (size_t)j * 1536, lane);
                ldact(A, p.mbuf, lane);
                v += gatedot(A, p.Wc + (size_t)j * 1536 + 512, lane);
            } else {
                ldact(A, p.mbuf + 16 * 512, lane);
                v = gatedot(A, p.Wc + (size_t)j * 1536 + 1024, lane);
            }
            if ((lane & 3) == 0) {
                int b = (lane >> 2) & 15;
                cc[jj][part][b] = v;
            }
            __syncthreads();
            if (tid < 32) {
                int b = tid & 15, jj2 = tid >> 4;
                int j2 = bid * 2 + jj2;
                p.comppre[b * 512 + j2] = cc[jj2][0][b] + cc[jj2][1][b] + p.bc[j2];
            }
        }
        gridbar(p.bar, ++tgt);

        // ========= stage D: softmax(comppre) folded into write-LSTM
        {
            int b = tid >> 4, g16 = tid & 15;
            float mxs = -1e30f;
            for (int i = g16; i < 512; i += 16)
                mxs = fmaxf(mxs, p.comppre[b * 512 + i]);
            #pragma unroll
            for (int d = 1; d < 16; d <<= 1) mxs = fmaxf(mxs, __shfl_xor(mxs, d, 64));
            if (g16 == 0) smx[b] = mxs;
            __syncthreads();
            float mxb = smx[b];
            float ssum = 0.f;
            for (int i = g16; i < 512; i += 16)
                ssum += __expf(p.comppre[b * 512 + i] - mxb);
            #pragma unroll
            for (int d = 1; d < 16; d <<= 1) ssum += __shfl_xor(ssum, d, 64);
            if (g16 == 0) sinv[b] = 1.0f / ssum;
            __syncthreads();

            f8 E[16];
            #pragma unroll
            for (int b2 = 0; b2 < 16; ++b2) {
                f8 v = ld8(p.comppre + b2 * 512 + lane * 8);
                float m2 = smx[b2];
                E[b2].a.x = __expf(v.a.x - m2); E[b2].a.y = __expf(v.a.y - m2);
                E[b2].a.z = __expf(v.a.z - m2); E[b2].a.w = __expf(v.a.w - m2);
                E[b2].b.x = __expf(v.b.x - m2); E[b2].b.y = __expf(v.b.y - m2);
                E[b2].b.z = __expf(v.b.z - m2); E[b2].b.w = __expf(v.b.w - m2);
            }
            int j0 = wv * 512 + u0;
            float ti0 = gatedot(E, p.Wih_w + (size_t)j0 * 512, lane);
            float ti1 = gatedot(E, p.Wih_w + (size_t)(j0 + 1) * 512, lane);
            if ((lane & 3) == 0) {
                int bb = (lane >> 2) & 15;
                gsm[0][wv][bb] = ti0 * sinv[bb] + vh0 + p.bih_w[j0] + p.bhh_w[j0];
                gsm[1][wv][bb] = ti1 * sinv[bb] + vh1 + p.bih_w[j0 + 1] + p.bhh_w[j0 + 1];
            }
            __syncthreads();
            if (tid < 32) {
                int bb = tid & 15, uu = tid >> 4;
                int u = u0 + uu;
                float gi = sigmoidf_(gsm[uu][0][bb]);
                float gf = sigmoidf_(gsm[uu][1][bb]);
                float gg = tanhf(gsm[uu][2][bb]);
                float go = sigmoidf_(gsm[uu][3][bb]);
                float cprev = (t == 0) ? p.cw0[bb * 512 + u] : p.cwS[bb * 512 + u];
                float c = gf * cprev + gi * gg;
                p.cwS[bb * 512 + u] = c;
                float h = go * tanhf(c);
                hwnext[bb * 512 + u] = h;
                p.outputs[(size_t)t * 8192 + bb * 512 + u] = h;
            }
        }
        gridbar(p.bar, ++tgt);
    }

    // ---- epilogue: final deferred M update with (z_63, hw_63 = hwb1);
    //      write LDS M -> d_out Mf region (the only M global write)
    {
        f8 w8 = ld8s(p.hwb1 + (size_t)bM * 512, lane);
        #pragma unroll
        for (int ii = 0; ii < 8; ++ii) {
            int rl = wv * 8 + ii;
            float zf = 1.0f - p.zbuf[bid * 32 + rl];
            f8 m;
            m.a = *(float4*)&Mlds[rl][lane * 4];
            m.b = *(float4*)&Mlds[rl][256 + lane * 4];
            upd8(m, w8, zf);
            st8s(p.Mw + (size_t)(bid * 32 + rl) * 512, m, lane);
        }
    }
    // hr_63 in hrb1 (= d_out hr slot), hw_63 in hwb1 (= d_out hw slot),
    // cr/cw updated in place in d_out. Kernel-end flush publishes everything.
}

extern "C" void kernel_launch(void* const* d_in, const int* in_sizes, int n_in,
                              void* d_out, int out_size, void* d_ws, size_t ws_size,
                              hipStream_t stream) {
    const float* emb   = (const float*)d_in[0];
    const float* hr0   = (const float*)d_in[1];
    const float* cr0   = (const float*)d_in[2];
    const float* hw0   = (const float*)d_in[3];
    const float* cw0   = (const float*)d_in[4];
    const float* io    = (const float*)d_in[5];
    const float* M0    = (const float*)d_in[6];
    const float* Wih_r = (const float*)d_in[7];
    const float* bih_r = (const float*)d_in[9];
    const float* bhh_r = (const float*)d_in[10];

    float* out = (float*)d_out;
    float* outputs = out;                    // [64][16][512]
    float* hrS1 = out + 524288;              // hr slot doubles as hr parity-1 buf
    float* crS  = out + 532480;              // cr (in-place state)
    float* hwS1 = out + 540672;              // hw slot doubles as hw parity-1 buf
    float* cwS  = out + 548864;              // cw (in-place state)
    float* Mw   = out + 557056;              // Mf (written once at epilogue)

    float* ws = (float*)d_ws;
    float* pre     = ws;                     // 1024*2048
    float* simbuf  = ws + 2097152;           // 8192
    float* zbuf    = simbuf + 8192;          // 8192
    float* mbuf    = zbuf + 8192;            // 32*512
    float* comppre = mbuf + 16384;           // 16*512
    float* hrB0    = comppre + 8192;         // 8192 (hr parity 0)
    float* hwB0    = hrB0 + 8192;            // 8192 (hw parity 0)
    float* mpart   = hwB0 + 8192;            // 256*512
    float* mxpart  = mpart + 131072;         // 256
    unsigned* bar  = (unsigned*)(mxpart + 256); // 8 grp + master + gen (640 uints)

    (void)hipMemsetAsync(bar, 0, 640 * sizeof(unsigned), stream);

    k_pre<<<dim3(32, 16), 256, 0, stream>>>(emb, io, Wih_r, bih_r, bhh_r, pre);

    P p;
    p.pre = pre;
    p.Whh_r = (const float*)d_in[8];
    p.Wc    = (const float*)d_in[11];
    p.bc    = (const float*)d_in[12];
    p.Wih_w = (const float*)d_in[13];
    p.Whh_w = (const float*)d_in[14];
    p.bih_w = (const float*)d_in[15];
    p.bhh_w = (const float*)d_in[16];
    p.hr0 = hr0; p.cr0 = cr0; p.hw0 = hw0; p.cw0 = cw0; p.M0 = M0;
    p.simbuf = simbuf; p.zbuf = zbuf; p.mbuf = mbuf; p.comppre = comppre;
    p.mpart = mpart; p.mxpart = mxpart;
    p.hrb0 = hrB0; p.hrb1 = hrS1; p.crS = crS;
    p.hwb0 = hwB0; p.hwb1 = hwS1; p.cwS = cwS;
    p.outputs = outputs; p.Mw = Mw;
    p.bar = bar;

    k_persist<<<NBLK, 256, 0, stream>>>(p);
}

// Round 7
// 4279.816 us; speedup vs baseline: 1.5205x; 1.0588x over previous
//
#include <hip/hip_runtime.h>
#include <math.h>

#define RR 512
#define BB 16
#define TT 64
#define KC 2
#define NN 256
#define NBLK 256

__device__ __forceinline__ float sigmoidf_(float x) {
    return 1.0f / (1.0f + __expf(-x));
}

__device__ __forceinline__ float wave_sum(float v) {
    #pragma unroll
    for (int off = 32; off > 0; off >>= 1) v += __shfl_xor(v, off, 64);
    return v;
}

struct f8 { float4 a, b; };
__device__ __forceinline__ f8 ld8(const float* p) {
    f8 r; r.a = ((const float4*)p)[0]; r.b = ((const float4*)p)[1]; return r;
}
// split-slice: thread's 8 floats of a 512-row are [lane*4,+4) and [256+lane*4,+4)
__device__ __forceinline__ f8 ld8s(const float* row, int lane) {
    f8 r;
    r.a = *(const float4*)(row + lane * 4);
    r.b = *(const float4*)(row + 256 + lane * 4);
    return r;
}
__device__ __forceinline__ void st8s(float* row, const f8& v, int lane) {
    *(float4*)(row + lane * 4) = v.a;
    *(float4*)(row + 256 + lane * 4) = v.b;
}
__device__ __forceinline__ float dot8(const f8& x, const f8& y) {
    return x.a.x*y.a.x + x.a.y*y.a.y + x.a.z*y.a.z + x.a.w*y.a.w
         + x.b.x*y.b.x + x.b.y*y.b.y + x.b.z*y.b.z + x.b.w*y.b.w;
}
// inline function, NOT a macro (macro param `w` collides with float4::w)
__device__ __forceinline__ void upd8(f8& m, const f8& u, float zf) {
    m.a.x = zf * (m.a.x + u.a.x); m.a.y = zf * (m.a.y + u.a.y);
    m.a.z = zf * (m.a.z + u.a.z); m.a.w = zf * (m.a.w + u.a.w);
    m.b.x = zf * (m.b.x + u.b.x); m.b.y = zf * (m.b.y + u.b.y);
    m.b.z = zf * (m.b.z + u.b.z); m.b.w = zf * (m.b.w + u.b.w);
}
__device__ __forceinline__ void fmaacc8(f8& acc, float sc, const f8& m, float wgt) {
    acc.a.x = acc.a.x*sc + wgt*m.a.x; acc.a.y = acc.a.y*sc + wgt*m.a.y;
    acc.a.z = acc.a.z*sc + wgt*m.a.z; acc.a.w = acc.a.w*sc + wgt*m.a.w;
    acc.b.x = acc.b.x*sc + wgt*m.b.x; acc.b.y = acc.b.y*sc + wgt*m.b.y;
    acc.b.z = acc.b.z*sc + wgt*m.b.z; acc.b.w = acc.b.w*sc + wgt*m.b.w;
}

// Payload-halving butterfly: p[0..15] per-b partials across 64 lanes ->
// each lane returns the full sum for b = (lane>>2)&15.
__device__ __forceinline__ float reduce16(float* p, int lane) {
    float q[8];
    {
        bool hi = (lane & 32) != 0;
        #pragma unroll
        for (int i = 0; i < 8; ++i) {
            float snd = hi ? p[i] : p[i + 8];
            float r = __shfl_xor(snd, 32, 64);
            q[i] = (hi ? p[i + 8] : p[i]) + r;
        }
    }
    float s4[4];
    {
        bool hi = (lane & 16) != 0;
        #pragma unroll
        for (int i = 0; i < 4; ++i) {
            float snd = hi ? q[i] : q[i + 4];
            float r = __shfl_xor(snd, 16, 64);
            s4[i] = (hi ? q[i + 4] : q[i]) + r;
        }
    }
    float d2[2];
    {
        bool hi = (lane & 8) != 0;
        #pragma unroll
        for (int i = 0; i < 2; ++i) {
            float snd = hi ? s4[i] : s4[i + 2];
            float r = __shfl_xor(snd, 8, 64);
            d2[i] = (hi ? s4[i + 2] : s4[i]) + r;
        }
    }
    float v;
    {
        bool hi = (lane & 4) != 0;
        float snd = hi ? d2[0] : d2[1];
        float r = __shfl_xor(snd, 4, 64);
        v = (hi ? d2[1] : d2[0]) + r;
    }
    v += __shfl_xor(v, 2, 64);
    v += __shfl_xor(v, 1, 64);
    return v;
}

// batched 16-b GEMV dot with REGISTER-resident weight slice
__device__ __forceinline__ float gatedotR(const f8* A, const f8& w, int lane) {
    float p[16];
    #pragma unroll
    for (int b = 0; b < 16; ++b) p[b] = dot8(A[b], w);
    return reduce16(p, lane);
}
__device__ __forceinline__ void ldact(f8* A, const float* act, int lane) {
    #pragma unroll
    for (int b = 0; b < 16; ++b) A[b] = ld8(act + b * 512 + lane * 8);
}

// ---- hierarchical grid barrier: arrivals 32/XCD-group -> 8 masters; release
// fans out via per-XCD xgen lines (31 spinners/line, L2-local if bid&7==XCD).
// bar layout (uints): xcnt[x] at x*16, xgen[x] at 128+x*16, mcnt at 256,
// mgen at 272, gcnt[kb] at 320+kb*16, ggen[kb] at 832+kb*16.  total 1344.
__device__ __forceinline__ void gridbarH(unsigned* bar, unsigned tgt, int bid) {
    __syncthreads();
    if (threadIdx.x == 0) {
        int x = bid & 7;
        unsigned* xcnt = bar + x * 16;
        unsigned* xgen = bar + 128 + x * 16;
        unsigned* mcnt = bar + 256;
        unsigned* mgen = bar + 272;
        unsigned a = __hip_atomic_fetch_add(xcnt, 1u, __ATOMIC_ACQ_REL,
                                            __HIP_MEMORY_SCOPE_AGENT);
        if (a == 31u) {
            __hip_atomic_store(xcnt, 0u, __ATOMIC_RELAXED, __HIP_MEMORY_SCOPE_AGENT);
            unsigned m = __hip_atomic_fetch_add(mcnt, 1u, __ATOMIC_ACQ_REL,
                                                __HIP_MEMORY_SCOPE_AGENT);
            if (m == 7u) {
                __hip_atomic_store(mcnt, 0u, __ATOMIC_RELAXED, __HIP_MEMORY_SCOPE_AGENT);
                __hip_atomic_store(mgen, tgt, __ATOMIC_RELEASE, __HIP_MEMORY_SCOPE_AGENT);
            } else {
                while (__hip_atomic_load(mgen, __ATOMIC_RELAXED,
                                         __HIP_MEMORY_SCOPE_AGENT) < tgt)
                    __builtin_amdgcn_s_sleep(1);
                (void)__hip_atomic_load(mgen, __ATOMIC_ACQUIRE, __HIP_MEMORY_SCOPE_AGENT);
            }
            __hip_atomic_store(xgen, tgt, __ATOMIC_RELEASE, __HIP_MEMORY_SCOPE_AGENT);
        } else {
            while (__hip_atomic_load(xgen, __ATOMIC_RELAXED,
                                     __HIP_MEMORY_SCOPE_AGENT) < tgt)
                __builtin_amdgcn_s_sleep(1);
            (void)__hip_atomic_load(xgen, __ATOMIC_ACQUIRE, __HIP_MEMORY_SCOPE_AGENT);
        }
    }
    __syncthreads();
}

// 8-block group barrier (one (k,b) group; blocks are bid = x + 8*w2 + 64*q,
// i.e. same residue mod 8 -> same XCD under round-robin dispatch).
__device__ __forceinline__ void groupbar(unsigned* bar, int kb, unsigned tgt) {
    __syncthreads();
    if (threadIdx.x == 0) {
        unsigned* gcnt = bar + 320 + kb * 16;
        unsigned* ggen = bar + 832 + kb * 16;
        unsigned a = __hip_atomic_fetch_add(gcnt, 1u, __ATOMIC_ACQ_REL,
                                            __HIP_MEMORY_SCOPE_AGENT);
        if (a == 7u) {
            __hip_atomic_store(gcnt, 0u, __ATOMIC_RELAXED, __HIP_MEMORY_SCOPE_AGENT);
            __hip_atomic_store(ggen, tgt, __ATOMIC_RELEASE, __HIP_MEMORY_SCOPE_AGENT);
        } else {
            while (__hip_atomic_load(ggen, __ATOMIC_RELAXED,
                                     __HIP_MEMORY_SCOPE_AGENT) < tgt)
                __builtin_amdgcn_s_sleep(1);
            (void)__hip_atomic_load(ggen, __ATOMIC_ACQUIRE, __HIP_MEMORY_SCOPE_AGENT);
        }
    }
    __syncthreads();
}

// ---------------------------------------------------------------------------
// k_pre: pre[t*16+b][j] = [emb|io] @ Wih_r^T + bih_r + bhh_r   (proven r1-r6)
// ---------------------------------------------------------------------------
__global__ void k_pre(const float* __restrict__ emb, const float* __restrict__ io,
                      const float* __restrict__ Wih, const float* __restrict__ bih,
                      const float* __restrict__ bhh, float* __restrict__ pre)
{
    __shared__ float As[16][65];
    __shared__ float Bs[16][65];
    int tid = threadIdx.x;
    int row0 = blockIdx.y * 64;
    int col0 = blockIdx.x * 64;
    int ty = tid >> 4, tx = tid & 15;
    float acc[4][4] = {};
    int lr = tid >> 2;
    int lk4 = (tid & 3) * 4;
    for (int k0 = 0; k0 < 1024; k0 += 16) {
        int grow = row0 + lr;
        int b = grow & 15;
        #pragma unroll
        for (int q = 0; q < 4; ++q) {
            int k = k0 + lk4 + q;
            float v = (k < RR) ? emb[(size_t)grow * RR + k]
                               : io[(size_t)b * RR + (k - RR)];
            As[lk4 + q][lr] = v;
        }
        #pragma unroll
        for (int q = 0; q < 4; ++q) {
            int k = k0 + lk4 + q;
            Bs[lk4 + q][lr] = Wih[(size_t)(col0 + lr) * 1024 + k];
        }
        __syncthreads();
        #pragma unroll
        for (int kk = 0; kk < 16; ++kk) {
            float a[4], bbv[4];
            #pragma unroll
            for (int i = 0; i < 4; ++i) a[i] = As[kk][ty * 4 + i];
            #pragma unroll
            for (int j = 0; j < 4; ++j) bbv[j] = Bs[kk][tx * 4 + j];
            #pragma unroll
            for (int i = 0; i < 4; ++i)
                #pragma unroll
                for (int j = 0; j < 4; ++j)
                    acc[i][j] += a[i] * bbv[j];
        }
        __syncthreads();
    }
    #pragma unroll
    for (int i = 0; i < 4; ++i) {
        int grow = row0 + ty * 4 + i;
        #pragma unroll
        for (int j = 0; j < 4; ++j) {
            int gcol = col0 + tx * 4 + j;
            pre[(size_t)grow * 2048 + gcol] = acc[i][j] + bih[gcol] + bhh[gcol];
        }
    }
}

struct P {
    const float *pre, *Whh_r, *Wc, *bc, *Wih_w, *Whh_w, *bih_w, *bhh_w;
    const float *hr0, *cr0, *hw0, *cw0, *M0;
    float *mbuf, *comppre, *mpart, *mxpart, *sumpart;
    float *hrb0, *hrb1, *crS, *hwb0, *hwb1, *cwS;
    float *outputs, *Mw;
    unsigned *bar;
};

// ---------------------------------------------------------------------------
// Persistent kernel: 64-step recurrence. M + sim in LDS; weights in registers;
// 3 hierarchical grid barriers + 1 XCD-local group barrier per step.
// ---------------------------------------------------------------------------
__global__ void __launch_bounds__(256, 1) k_persist(P p)
{
    const int tid = threadIdx.x;
    const int bid = blockIdx.x;
    const int wv = tid >> 6;
    const int lane = tid & 63;
    const int u0 = bid * 2;               // 2 u-columns for LSTM/comp stages
    const int kb = (bid & 7) * 4 + (bid >> 6);   // (k,b) group: same XCD
    const int w2 = (bid >> 3) & 7;               // slot within group
    const int bM = kb & 15;               // batch index of this block's M rows
    const int rowG = kb * 256 + w2 * 32;  // first global M row of this block

    __shared__ float Mlds[32][512];       // 64 KB: block's 32 M rows
    __shared__ float smacc[4][512];       // stage-A online-m per-wave partials
    __shared__ float smx4[4], ssh4[4];
    __shared__ float simL[32];            // this block's sim values (for local z)
    __shared__ float gsm[2][4][16];       // [uu][gate][b]
    __shared__ float cc[2][2][16];        // stage-C partial combine [jj][part][b]
    __shared__ float smx[16], sinv[16];
    __shared__ float bcsh[2];

    unsigned tg = 0;
    float mxK = 0.f, sumInvK = 0.f;       // group softmax stats of previous step

    // ---- register-resident weight slices (read once, reused 64 steps)
    const int jA = wv * 512 + u0;         // gate-row pair for this wave
    const f8 wR0 = ld8(p.Whh_r + (size_t)jA * 512 + lane * 8);
    const f8 wR1 = ld8(p.Whh_r + (size_t)(jA + 1) * 512 + lane * 8);
    const f8 wW0 = ld8(p.Whh_w + (size_t)jA * 512 + lane * 8);
    const f8 wW1 = ld8(p.Whh_w + (size_t)(jA + 1) * 512 + lane * 8);
    const f8 wI0 = ld8(p.Wih_w + (size_t)jA * 512 + lane * 8);
    const f8 wI1 = ld8(p.Wih_w + (size_t)(jA + 1) * 512 + lane * 8);
    const float bw0 = p.bih_w[jA] + p.bhh_w[jA];
    const float bw1 = p.bih_w[jA + 1] + p.bhh_w[jA + 1];
    const int jj = wv >> 1, part = wv & 1;
    const int jC = u0 + jj;
    f8 wC0, wC1 = {};
    if (part == 0) {
        wC0 = ld8(p.Wc + (size_t)jC * 1536 + lane * 8);
        wC1 = ld8(p.Wc + (size_t)jC * 1536 + 512 + lane * 8);
    } else {
        wC0 = ld8(p.Wc + (size_t)jC * 1536 + 1024 + lane * 8);
    }
    if (tid < 2) bcsh[tid] = p.bc[u0 + tid];

    // ---- load this block's M rows: global M0 -> LDS (once)
    {
        const float4* src = (const float4*)(p.M0 + (size_t)rowG * 512);
        float4* dst = (float4*)&Mlds[0][0];
        #pragma unroll 4
        for (int idx = tid; idx < 32 * 128; idx += 256)
            dst[idx] = src[idx];
    }

    // ---- prologue: read-LSTM step 0 -> hr_0 (hrb0), c_0 (crS)
    {
        f8 A[16]; ldact(A, p.hr0, lane);
        float gv0 = gatedotR(A, wR0, lane);
        float gv1 = gatedotR(A, wR1, lane);
        if ((lane & 3) == 0) {
            int b = (lane >> 2) & 15;
            gsm[0][wv][b] = gv0 + p.pre[(size_t)b * 2048 + jA];
            gsm[1][wv][b] = gv1 + p.pre[(size_t)b * 2048 + jA + 1];
        }
        __syncthreads();
        if (tid < 32) {
            int b = tid & 15, uu = tid >> 4;
            int u = u0 + uu;
            float gi = sigmoidf_(gsm[uu][0][b]);
            float gf = sigmoidf_(gsm[uu][1][b]);
            float gg = tanhf(gsm[uu][2][b]);
            float go = sigmoidf_(gsm[uu][3][b]);
            float c = gf * p.cr0[b * 512 + u] + gi * gg;
            p.crS[b * 512 + u] = c;
            p.hrb0[b * 512 + u] = go * tanhf(c);
        }
        gridbarH(p.bar, ++tg, bid);
    }

    for (int t = 0; t < TT; ++t) {
        const float* hrcur  = (t & 1) ? p.hrb1 : p.hrb0;   // hr_t
        float*       hrnext = (t & 1) ? p.hrb0 : p.hrb1;   // hr_{t+1}
        const float* hwprev = (t == 0) ? p.hw0 : (((t - 1) & 1) ? p.hwb1 : p.hwb0);
        float*       hwnext = (t & 1) ? p.hwb1 : p.hwb0;   // hw_t

        // ========= stage A: deferred M update (local z) + sim + online partials
        {
            f8 h = ld8s(hrcur + (size_t)bM * 512, lane);
            f8 w8 = {};
            if (t > 0) w8 = ld8s(hwprev + (size_t)bM * 512, lane);
            float mx = -3.0e38f, ssum = 0.f;
            f8 macc = {};
            #pragma unroll
            for (int ii = 0; ii < 8; ++ii) {
                int rl = wv * 8 + ii;
                float4* mp0 = (float4*)&Mlds[rl][lane * 4];
                float4* mp1 = (float4*)&Mlds[rl][256 + lane * 4];
                f8 m; m.a = *mp0; m.b = *mp1;
                if (t > 0) {
                    float zf = 1.0f - __expf(simL[rl] - mxK) * sumInvK;
                    upd8(m, w8, zf);
                    *mp0 = m.a; *mp1 = m.b;
                }
                float s = wave_sum(dot8(m, h));
                float nmx = fmaxf(mx, s);
                float sc = __expf(mx - nmx);     // first iter: exp(-inf)=0
                float wgt = __expf(s - nmx);
                fmaacc8(macc, sc, m, wgt);
                ssum = ssum * sc + wgt;
                mx = nmx;
                if (lane == 0) simL[rl] = s;
            }
            if (lane == 0) { smx4[wv] = mx; ssh4[wv] = ssum; }
            __syncthreads();
            float MXb = fmaxf(fmaxf(smx4[0], smx4[1]), fmaxf(smx4[2], smx4[3]));
            float sc2 = __expf(mx - MXb);
            float* d0 = &smacc[wv][lane * 4];
            float* d1 = &smacc[wv][256 + lane * 4];
            d0[0] = macc.a.x * sc2; d0[1] = macc.a.y * sc2;
            d0[2] = macc.a.z * sc2; d0[3] = macc.a.w * sc2;
            d1[0] = macc.b.x * sc2; d1[1] = macc.b.y * sc2;
            d1[2] = macc.b.z * sc2; d1[3] = macc.b.w * sc2;
            __syncthreads();
            for (int r = tid; r < 512; r += 256)
                p.mpart[(size_t)(kb * 8 + w2) * 512 + r] =
                    smacc[0][r] + smacc[1][r] + smacc[2][r] + smacc[3][r];
            if (tid == 0) {
                float sB = ssh4[0] * __expf(smx4[0] - MXb)
                         + ssh4[1] * __expf(smx4[1] - MXb)
                         + ssh4[2] * __expf(smx4[2] - MXb)
                         + ssh4[3] * __expf(smx4[3] - MXb);
                p.mxpart[kb * 8 + w2] = MXb;
                p.sumpart[kb * 8 + w2] = sB;
            }
        }
        // ========= stage A2: read-LSTM gates for t+1
        if (t < 63) {
            f8 A[16]; ldact(A, hrcur, lane);
            float gv0 = gatedotR(A, wR0, lane);
            float gv1 = gatedotR(A, wR1, lane);
            if ((lane & 3) == 0) {
                int b = (lane >> 2) & 15;
                gsm[0][wv][b] = gv0 + p.pre[(size_t)((t + 1) * 16 + b) * 2048 + jA];
                gsm[1][wv][b] = gv1 + p.pre[(size_t)((t + 1) * 16 + b) * 2048 + jA + 1];
            }
            __syncthreads();
            if (tid < 32) {
                int b = tid & 15, uu = tid >> 4;
                int u = u0 + uu;
                float gi = sigmoidf_(gsm[uu][0][b]);
                float gf = sigmoidf_(gsm[uu][1][b]);
                float gg = tanhf(gsm[uu][2][b]);
                float go = sigmoidf_(gsm[uu][3][b]);
                float c = gf * p.crS[b * 512 + u] + gi * gg;
                p.crS[b * 512 + u] = c;
                hrnext[b * 512 + u] = go * tanhf(c);
            }
        }

        // ========= stage B-lite: group (k,b) softmax stats + mbuf slice
        groupbar(p.bar, kb, (unsigned)(t + 1));
        {
            float MX = -3.0e38f;
            #pragma unroll
            for (int w3 = 0; w3 < 8; ++w3)
                MX = fmaxf(MX, p.mxpart[kb * 8 + w3]);
            float SUM = 0.f;
            #pragma unroll
            for (int w3 = 0; w3 < 8; ++w3)
                SUM += p.sumpart[kb * 8 + w3] * __expf(p.mxpart[kb * 8 + w3] - MX);
            mxK = MX;
            sumInvK = 1.0f / SUM;
            if (tid < 64) {
                int r = w2 * 64 + tid;
                float acc = 0.f;
                #pragma unroll
                for (int w3 = 0; w3 < 8; ++w3)
                    acc += __expf(p.mxpart[kb * 8 + w3] - MX)
                         * p.mpart[(size_t)(kb * 8 + w3) * 512 + r];
                p.mbuf[(size_t)kb * 512 + r] = acc * sumInvK;
            }
        }
        gridbarH(p.bar, ++tg, bid);

        // ========= stage C: comppre GEMV + hoisted vh = hw_prev . Whh_w
        float vh0, vh1;
        {
            f8 H[16]; ldact(H, hwprev, lane);
            vh0 = gatedotR(H, wW0, lane);
            vh1 = gatedotR(H, wW1, lane);
        }
        {
            float v;
            f8 A[16];
            if (part == 0) {
                ldact(A, hrcur, lane);
                v = gatedotR(A, wC0, lane);
                ldact(A, p.mbuf, lane);
                v += gatedotR(A, wC1, lane);
            } else {
                ldact(A, p.mbuf + 16 * 512, lane);
                v = gatedotR(A, wC0, lane);
            }
            if ((lane & 3) == 0) {
                int b = (lane >> 2) & 15;
                cc[jj][part][b] = v;
            }
            __syncthreads();
            if (tid < 32) {
                int b = tid & 15, jj2 = tid >> 4;
                p.comppre[b * 512 + (u0 + jj2)] =
                    cc[jj2][0][b] + cc[jj2][1][b] + bcsh[jj2];
            }
        }
        gridbarH(p.bar, ++tg, bid);

        // ========= stage D: softmax(comppre) folded into write-LSTM
        {
            int b = tid >> 4, g16 = tid & 15;
            float mxs = -1e30f;
            for (int i = g16; i < 512; i += 16)
                mxs = fmaxf(mxs, p.comppre[b * 512 + i]);
            #pragma unroll
            for (int d = 1; d < 16; d <<= 1) mxs = fmaxf(mxs, __shfl_xor(mxs, d, 64));
            if (g16 == 0) smx[b] = mxs;
            __syncthreads();
            float mxb = smx[b];
            float ssum = 0.f;
            for (int i = g16; i < 512; i += 16)
                ssum += __expf(p.comppre[b * 512 + i] - mxb);
            #pragma unroll
            for (int d = 1; d < 16; d <<= 1) ssum += __shfl_xor(ssum, d, 64);
            if (g16 == 0) sinv[b] = 1.0f / ssum;
            __syncthreads();

            f8 E[16];
            #pragma unroll
            for (int b2 = 0; b2 < 16; ++b2) {
                f8 v = ld8(p.comppre + b2 * 512 + lane * 8);
                float m2 = smx[b2];
                E[b2].a.x = __expf(v.a.x - m2); E[b2].a.y = __expf(v.a.y - m2);
                E[b2].a.z = __expf(v.a.z - m2); E[b2].a.w = __expf(v.a.w - m2);
                E[b2].b.x = __expf(v.b.x - m2); E[b2].b.y = __expf(v.b.y - m2);
                E[b2].b.z = __expf(v.b.z - m2); E[b2].b.w = __expf(v.b.w - m2);
            }
            float ti0 = gatedotR(E, wI0, lane);
            float ti1 = gatedotR(E, wI1, lane);
            if ((lane & 3) == 0) {
                int bb = (lane >> 2) & 15;
                gsm[0][wv][bb] = ti0 * sinv[bb] + vh0 + bw0;
                gsm[1][wv][bb] = ti1 * sinv[bb] + vh1 + bw1;
            }
            __syncthreads();
            if (tid < 32) {
                int bb = tid & 15, uu = tid >> 4;
                int u = u0 + uu;
                float gi = sigmoidf_(gsm[uu][0][bb]);
                float gf = sigmoidf_(gsm[uu][1][bb]);
                float gg = tanhf(gsm[uu][2][bb]);
                float go = sigmoidf_(gsm[uu][3][bb]);
                float cprev = (t == 0) ? p.cw0[bb * 512 + u] : p.cwS[bb * 512 + u];
                float c = gf * cprev + gi * gg;
                p.cwS[bb * 512 + u] = c;
                float h = go * tanhf(c);
                hwnext[bb * 512 + u] = h;
                p.outputs[(size_t)t * 8192 + bb * 512 + u] = h;
            }
        }
        gridbarH(p.bar, ++tg, bid);
    }

    // ---- epilogue: final deferred M update with (z_63, hw_63 = hwb1);
    //      write LDS M -> d_out Mf region (the only M global write)
    {
        f8 w8 = ld8s(p.hwb1 + (size_t)bM * 512, lane);
        #pragma unroll
        for (int ii = 0; ii < 8; ++ii) {
            int rl = wv * 8 + ii;
            float zf = 1.0f - __expf(simL[rl] - mxK) * sumInvK;
            f8 m;
            m.a = *(float4*)&Mlds[rl][lane * 4];
            m.b = *(float4*)&Mlds[rl][256 + lane * 4];
            upd8(m, w8, zf);
            st8s(p.Mw + (size_t)(rowG + rl) * 512, m, lane);
        }
    }
}

extern "C" void kernel_launch(void* const* d_in, const int* in_sizes, int n_in,
                              void* d_out, int out_size, void* d_ws, size_t ws_size,
                              hipStream_t stream) {
    const float* emb   = (const float*)d_in[0];
    const float* hr0   = (const float*)d_in[1];
    const float* cr0   = (const float*)d_in[2];
    const float* hw0   = (const float*)d_in[3];
    const float* cw0   = (const float*)d_in[4];
    const float* io    = (const float*)d_in[5];
    const float* M0    = (const float*)d_in[6];
    const float* Wih_r = (const float*)d_in[7];
    const float* bih_r = (const float*)d_in[9];
    const float* bhh_r = (const float*)d_in[10];

    float* out = (float*)d_out;
    float* outputs = out;                    // [64][16][512]
    float* hrS1 = out + 524288;              // hr slot doubles as hr parity-1 buf
    float* crS  = out + 532480;              // cr (in-place state)
    float* hwS1 = out + 540672;              // hw slot doubles as hw parity-1 buf
    float* cwS  = out + 548864;              // cw (in-place state)
    float* Mw   = out + 557056;              // Mf (written once at epilogue)

    float* ws = (float*)d_ws;
    float* pre     = ws;                     // 1024*2048
    float* mbuf    = ws + 2097152;           // 32*512
    float* comppre = mbuf + 16384;           // 16*512
    float* hrB0    = comppre + 8192;         // 8192 (hr parity 0)
    float* hwB0    = hrB0 + 8192;            // 8192 (hw parity 0)
    float* mpart   = hwB0 + 8192;            // 256*512
    float* mxpart  = mpart + 131072;         // 256
    float* sumpart = mxpart + 256;           // 256
    unsigned* bar  = (unsigned*)(sumpart + 256); // 1344 uints

    (void)hipMemsetAsync(bar, 0, 1344 * sizeof(unsigned), stream);

    k_pre<<<dim3(32, 16), 256, 0, stream>>>(emb, io, Wih_r, bih_r, bhh_r, pre);

    P p;
    p.pre = pre;
    p.Whh_r = (const float*)d_in[8];
    p.Wc    = (const float*)d_in[11];
    p.bc    = (const float*)d_in[12];
    p.Wih_w = (const float*)d_in[13];
    p.Whh_w = (const float*)d_in[14];
    p.bih_w = (const float*)d_in[15];
    p.bhh_w = (const float*)d_in[16];
    p.hr0 = hr0; p.cr0 = cr0; p.hw0 = hw0; p.cw0 = cw0; p.M0 = M0;
    p.mbuf = mbuf; p.comppre = comppre;
    p.mpart = mpart; p.mxpart = mxpart; p.sumpart = sumpart;
    p.hrb0 = hrB0; p.hrb1 = hrS1; p.crS = crS;
    p.hwb0 = hwB0; p.hwb1 = hwS1; p.cwS = cwS;
    p.outputs = outputs; p.Mw = Mw;
    p.bar = bar;

    k_persist<<<NBLK, 256, 0, stream>>>(p);
}

// Round 8
// 3757.932 us; speedup vs baseline: 1.7317x; 1.1389x over previous
//
#include <hip/hip_runtime.h>
#include <math.h>

#define RR 512
#define BB 16
#define TT 64
#define KC 2
#define NN 256
#define NBLK 256

__device__ __forceinline__ float sigmoidf_(float x) {
    return 1.0f / (1.0f + __expf(-x));
}

__device__ __forceinline__ float wave_sum(float v) {
    #pragma unroll
    for (int off = 32; off > 0; off >>= 1) v += __shfl_xor(v, off, 64);
    return v;
}

struct f8 { float4 a, b; };
__device__ __forceinline__ f8 ld8(const float* p) {
    f8 r; r.a = ((const float4*)p)[0]; r.b = ((const float4*)p)[1]; return r;
}
// split-slice: thread's 8 floats of a 512-row are [lane*4,+4) and [256+lane*4,+4)
__device__ __forceinline__ f8 ld8s(const float* row, int lane) {
    f8 r;
    r.a = *(const float4*)(row + lane * 4);
    r.b = *(const float4*)(row + 256 + lane * 4);
    return r;
}
__device__ __forceinline__ void st8s(float* row, const f8& v, int lane) {
    *(float4*)(row + lane * 4) = v.a;
    *(float4*)(row + 256 + lane * 4) = v.b;
}
__device__ __forceinline__ float dot8(const f8& x, const f8& y) {
    return x.a.x*y.a.x + x.a.y*y.a.y + x.a.z*y.a.z + x.a.w*y.a.w
         + x.b.x*y.b.x + x.b.y*y.b.y + x.b.z*y.b.z + x.b.w*y.b.w;
}
// inline function, NOT a macro (macro param `w` collides with float4::w)
__device__ __forceinline__ void upd8(f8& m, const f8& u, float zf) {
    m.a.x = zf * (m.a.x + u.a.x); m.a.y = zf * (m.a.y + u.a.y);
    m.a.z = zf * (m.a.z + u.a.z); m.a.w = zf * (m.a.w + u.a.w);
    m.b.x = zf * (m.b.x + u.b.x); m.b.y = zf * (m.b.y + u.b.y);
    m.b.z = zf * (m.b.z + u.b.z); m.b.w = zf * (m.b.w + u.b.w);
}
__device__ __forceinline__ void fmaacc8(f8& acc, float sc, const f8& m, float wgt) {
    acc.a.x = acc.a.x*sc + wgt*m.a.x; acc.a.y = acc.a.y*sc + wgt*m.a.y;
    acc.a.z = acc.a.z*sc + wgt*m.a.z; acc.a.w = acc.a.w*sc + wgt*m.a.w;
    acc.b.x = acc.b.x*sc + wgt*m.b.x; acc.b.y = acc.b.y*sc + wgt*m.b.y;
    acc.b.z = acc.b.z*sc + wgt*m.b.z; acc.b.w = acc.b.w*sc + wgt*m.b.w;
}

// Payload-halving butterfly: p[0..15] per-b partials across 64 lanes ->
// each lane returns the full sum for b = (lane>>2)&15.
__device__ __forceinline__ float reduce16(float* p, int lane) {
    float q[8];
    {
        bool hi = (lane & 32) != 0;
        #pragma unroll
        for (int i = 0; i < 8; ++i) {
            float snd = hi ? p[i] : p[i + 8];
            float r = __shfl_xor(snd, 32, 64);
            q[i] = (hi ? p[i + 8] : p[i]) + r;
        }
    }
    float s4[4];
    {
        bool hi = (lane & 16) != 0;
        #pragma unroll
        for (int i = 0; i < 4; ++i) {
            float snd = hi ? q[i] : q[i + 4];
            float r = __shfl_xor(snd, 16, 64);
            s4[i] = (hi ? q[i + 4] : q[i]) + r;
        }
    }
    float d2[2];
    {
        bool hi = (lane & 8) != 0;
        #pragma unroll
        for (int i = 0; i < 2; ++i) {
            float snd = hi ? s4[i] : s4[i + 2];
            float r = __shfl_xor(snd, 8, 64);
            d2[i] = (hi ? s4[i + 2] : s4[i]) + r;
        }
    }
    float v;
    {
        bool hi = (lane & 4) != 0;
        float snd = hi ? d2[0] : d2[1];
        float r = __shfl_xor(snd, 4, 64);
        v = (hi ? d2[1] : d2[0]) + r;
    }
    v += __shfl_xor(v, 2, 64);
    v += __shfl_xor(v, 1, 64);
    return v;
}

// batched 16-b GEMV dot with REGISTER-resident weight slice
__device__ __forceinline__ float gatedotR(const f8* A, const f8& w, int lane) {
    float p[16];
    #pragma unroll
    for (int b = 0; b < 16; ++b) p[b] = dot8(A[b], w);
    return reduce16(p, lane);
}
__device__ __forceinline__ void ldact(f8* A, const float* act, int lane) {
    #pragma unroll
    for (int b = 0; b < 16; ++b) A[b] = ld8(act + b * 512 + lane * 8);
}

// ---- hierarchical grid barrier (proven r7): arrivals 32/group -> 8 masters;
// release fans out via per-XCD xgen lines.
__device__ __forceinline__ void gridbarH(unsigned* bar, unsigned tgt, int bid) {
    __syncthreads();
    if (threadIdx.x == 0) {
        int x = bid & 7;
        unsigned* xcnt = bar + x * 16;
        unsigned* xgen = bar + 128 + x * 16;
        unsigned* mcnt = bar + 256;
        unsigned* mgen = bar + 272;
        unsigned a = __hip_atomic_fetch_add(xcnt, 1u, __ATOMIC_ACQ_REL,
                                            __HIP_MEMORY_SCOPE_AGENT);
        if (a == 31u) {
            __hip_atomic_store(xcnt, 0u, __ATOMIC_RELAXED, __HIP_MEMORY_SCOPE_AGENT);
            unsigned m = __hip_atomic_fetch_add(mcnt, 1u, __ATOMIC_ACQ_REL,
                                                __HIP_MEMORY_SCOPE_AGENT);
            if (m == 7u) {
                __hip_atomic_store(mcnt, 0u, __ATOMIC_RELAXED, __HIP_MEMORY_SCOPE_AGENT);
                __hip_atomic_store(mgen, tgt, __ATOMIC_RELEASE, __HIP_MEMORY_SCOPE_AGENT);
            } else {
                while (__hip_atomic_load(mgen, __ATOMIC_RELAXED,
                                         __HIP_MEMORY_SCOPE_AGENT) < tgt)
                    __builtin_amdgcn_s_sleep(1);
                (void)__hip_atomic_load(mgen, __ATOMIC_ACQUIRE, __HIP_MEMORY_SCOPE_AGENT);
            }
            __hip_atomic_store(xgen, tgt, __ATOMIC_RELEASE, __HIP_MEMORY_SCOPE_AGENT);
        } else {
            while (__hip_atomic_load(xgen, __ATOMIC_RELAXED,
                                     __HIP_MEMORY_SCOPE_AGENT) < tgt)
                __builtin_amdgcn_s_sleep(1);
            (void)__hip_atomic_load(xgen, __ATOMIC_ACQUIRE, __HIP_MEMORY_SCOPE_AGENT);
        }
    }
    __syncthreads();
}

// 8-block group barrier for one (k,b) group (same residue mod 8 -> same XCD)
__device__ __forceinline__ void groupbar(unsigned* bar, int kb, unsigned tgt) {
    __syncthreads();
    if (threadIdx.x == 0) {
        unsigned* gcnt = bar + 320 + kb * 16;
        unsigned* ggen = bar + 832 + kb * 16;
        unsigned a = __hip_atomic_fetch_add(gcnt, 1u, __ATOMIC_ACQ_REL,
                                            __HIP_MEMORY_SCOPE_AGENT);
        if (a == 7u) {
            __hip_atomic_store(gcnt, 0u, __ATOMIC_RELAXED, __HIP_MEMORY_SCOPE_AGENT);
            __hip_atomic_store(ggen, tgt, __ATOMIC_RELEASE, __HIP_MEMORY_SCOPE_AGENT);
        } else {
            while (__hip_atomic_load(ggen, __ATOMIC_RELAXED,
                                     __HIP_MEMORY_SCOPE_AGENT) < tgt)
                __builtin_amdgcn_s_sleep(1);
            (void)__hip_atomic_load(ggen, __ATOMIC_ACQUIRE, __HIP_MEMORY_SCOPE_AGENT);
        }
    }
    __syncthreads();
}

// ---------------------------------------------------------------------------
// k_pre: pre[t*16+b][j] = [emb|io] @ Wih_r^T + bih_r + bhh_r   (proven r1-r7)
// ---------------------------------------------------------------------------
__global__ void k_pre(const float* __restrict__ emb, const float* __restrict__ io,
                      const float* __restrict__ Wih, const float* __restrict__ bih,
                      const float* __restrict__ bhh, float* __restrict__ pre)
{
    __shared__ float As[16][65];
    __shared__ float Bs[16][65];
    int tid = threadIdx.x;
    int row0 = blockIdx.y * 64;
    int col0 = blockIdx.x * 64;
    int ty = tid >> 4, tx = tid & 15;
    float acc[4][4] = {};
    int lr = tid >> 2;
    int lk4 = (tid & 3) * 4;
    for (int k0 = 0; k0 < 1024; k0 += 16) {
        int grow = row0 + lr;
        int b = grow & 15;
        #pragma unroll
        for (int q = 0; q < 4; ++q) {
            int k = k0 + lk4 + q;
            float v = (k < RR) ? emb[(size_t)grow * RR + k]
                               : io[(size_t)b * RR + (k - RR)];
            As[lk4 + q][lr] = v;
        }
        #pragma unroll
        for (int q = 0; q < 4; ++q) {
            int k = k0 + lk4 + q;
            Bs[lk4 + q][lr] = Wih[(size_t)(col0 + lr) * 1024 + k];
        }
        __syncthreads();
        #pragma unroll
        for (int kk = 0; kk < 16; ++kk) {
            float a[4], bbv[4];
            #pragma unroll
            for (int i = 0; i < 4; ++i) a[i] = As[kk][ty * 4 + i];
            #pragma unroll
            for (int j = 0; j < 4; ++j) bbv[j] = Bs[kk][tx * 4 + j];
            #pragma unroll
            for (int i = 0; i < 4; ++i)
                #pragma unroll
                for (int j = 0; j < 4; ++j)
                    acc[i][j] += a[i] * bbv[j];
        }
        __syncthreads();
    }
    #pragma unroll
    for (int i = 0; i < 4; ++i) {
        int grow = row0 + ty * 4 + i;
        #pragma unroll
        for (int j = 0; j < 4; ++j) {
            int gcol = col0 + tx * 4 + j;
            pre[(size_t)grow * 2048 + gcol] = acc[i][j] + bih[gcol] + bhh[gcol];
        }
    }
}

struct P {
    const float *pre, *Whh_r, *Wc, *bc, *Wih_w, *Whh_w, *bih_w, *bhh_w;
    const float *hr0, *cr0, *hw0, *cw0, *M0;
    float *mbuf, *comppre, *mpart, *mxpart, *sumpart;
    float *hrb0, *hrb1, *crS, *hwb0, *hwb1, *cwS;
    float *outputs, *Mw;
    unsigned *bar;
};

// ---------------------------------------------------------------------------
// Persistent kernel: 64-step recurrence. M + staged activations in LDS;
// weights in registers; 3 grid + 1 group barrier per step.
// ---------------------------------------------------------------------------
__global__ void __launch_bounds__(256, 1) k_persist(P p)
{
    const int tid = threadIdx.x;
    const int bid = blockIdx.x;
    const int wv = tid >> 6;
    const int lane = tid & 63;
    const int u0 = bid * 2;               // 2 u-columns for LSTM/comp stages
    const int kb = (bid & 7) * 4 + (bid >> 6);   // (k,b) group: same XCD
    const int w2 = (bid >> 3) & 7;               // slot within group
    const int bM = kb & 15;               // batch index of this block's M rows
    const int rowG = kb * 256 + w2 * 32;  // first global M row of this block

    __shared__ float Mlds[32][512];       // 64 KB: block's 32 M rows
    __shared__ float actH[16 * 512];      // 32 KB: hr_t staged; E overlay in D
    __shared__ float actW[16 * 512];      // 32 KB: hw_{t-1} staged
    __shared__ float smacc[4][512];       // 8 KB: stage-A online-m partials
    __shared__ float smx4[4], ssh4[4];
    __shared__ float simL[32];
    __shared__ float gsm[2][4][16];       // [uu][gate][b]
    __shared__ float cc[2][2][16];        // stage-C partial combine
    __shared__ float sinv[16];
    __shared__ float bcsh[2];

    unsigned tg = 0;
    float mxK = 0.f, sumInvK = 0.f;       // group softmax stats of prev step

    // ---- register-resident weight slices (read once, reused 64 steps)
    const int jA = wv * 512 + u0;
    const f8 wR0 = ld8(p.Whh_r + (size_t)jA * 512 + lane * 8);
    const f8 wR1 = ld8(p.Whh_r + (size_t)(jA + 1) * 512 + lane * 8);
    const f8 wW0 = ld8(p.Whh_w + (size_t)jA * 512 + lane * 8);
    const f8 wW1 = ld8(p.Whh_w + (size_t)(jA + 1) * 512 + lane * 8);
    const f8 wI0 = ld8(p.Wih_w + (size_t)jA * 512 + lane * 8);
    const f8 wI1 = ld8(p.Wih_w + (size_t)(jA + 1) * 512 + lane * 8);
    const float bw0 = p.bih_w[jA] + p.bhh_w[jA];
    const float bw1 = p.bih_w[jA + 1] + p.bhh_w[jA + 1];
    const int jj = wv >> 1, part = wv & 1;
    const int jC = u0 + jj;
    f8 wC0, wC1 = {};
    if (part == 0) {
        wC0 = ld8(p.Wc + (size_t)jC * 1536 + lane * 8);
        wC1 = ld8(p.Wc + (size_t)jC * 1536 + 512 + lane * 8);
    } else {
        wC0 = ld8(p.Wc + (size_t)jC * 1536 + 1024 + lane * 8);
    }
    if (tid < 2) bcsh[tid] = p.bc[u0 + tid];

    // ---- load this block's M rows: global M0 -> LDS (once)
    {
        const float4* src = (const float4*)(p.M0 + (size_t)rowG * 512);
        float4* dst = (float4*)&Mlds[0][0];
        #pragma unroll 4
        for (int idx = tid; idx < 32 * 128; idx += 256)
            dst[idx] = src[idx];
    }

    // ---- prologue: read-LSTM step 0 -> hr_0 (hrb0), c_0 (crS)
    {
        f8 A[16]; ldact(A, p.hr0, lane);
        float gv0 = gatedotR(A, wR0, lane);
        float gv1 = gatedotR(A, wR1, lane);
        if ((lane & 3) == 0) {
            int b = (lane >> 2) & 15;
            gsm[0][wv][b] = gv0 + p.pre[(size_t)b * 2048 + jA];
            gsm[1][wv][b] = gv1 + p.pre[(size_t)b * 2048 + jA + 1];
        }
        __syncthreads();
        if (tid < 32) {
            int b = tid & 15, uu = tid >> 4;
            int u = u0 + uu;
            float gi = sigmoidf_(gsm[uu][0][b]);
            float gf = sigmoidf_(gsm[uu][1][b]);
            float gg = tanhf(gsm[uu][2][b]);
            float go = sigmoidf_(gsm[uu][3][b]);
            float c = gf * p.cr0[b * 512 + u] + gi * gg;
            p.crS[b * 512 + u] = c;
            p.hrb0[b * 512 + u] = go * tanhf(c);
        }
        gridbarH(p.bar, ++tg, bid);
    }

    for (int t = 0; t < TT; ++t) {
        const float* hrcur  = (t & 1) ? p.hrb1 : p.hrb0;   // hr_t
        float*       hrnext = (t & 1) ? p.hrb0 : p.hrb1;   // hr_{t+1}
        const float* hwprev = (t == 0) ? p.hw0 : (((t - 1) & 1) ? p.hwb1 : p.hwb0);
        float*       hwnext = (t & 1) ? p.hwb1 : p.hwb0;   // hw_t

        // ---- stage hr_t and hw_{t-1} into LDS (once per block per step)
        {
            const float4* s1 = (const float4*)hrcur;
            const float4* s2 = (const float4*)hwprev;
            float4* d1 = (float4*)actH;
            float4* d2 = (float4*)actW;
            #pragma unroll
            for (int q = 0; q < 8; ++q) {
                d1[tid + q * 256] = s1[tid + q * 256];
                d2[tid + q * 256] = s2[tid + q * 256];
            }
        }
        __syncthreads();

        // ========= stage A: deferred M update (local z) + sim + online partials
        {
            f8 h = ld8s(actH + bM * 512, lane);
            f8 w8 = {};
            if (t > 0) w8 = ld8s(actW + bM * 512, lane);
            float mx = -3.0e38f, ssum = 0.f;
            f8 macc = {};
            #pragma unroll
            for (int ii = 0; ii < 8; ++ii) {
                int rl = wv * 8 + ii;
                float4* mp0 = (float4*)&Mlds[rl][lane * 4];
                float4* mp1 = (float4*)&Mlds[rl][256 + lane * 4];
                f8 m; m.a = *mp0; m.b = *mp1;
                if (t > 0) {
                    float zf = 1.0f - __expf(simL[rl] - mxK) * sumInvK;
                    upd8(m, w8, zf);
                    *mp0 = m.a; *mp1 = m.b;
                }
                float s = wave_sum(dot8(m, h));
                float nmx = fmaxf(mx, s);
                float sc = __expf(mx - nmx);     // first iter: exp(-inf)=0
                float wgt = __expf(s - nmx);
                fmaacc8(macc, sc, m, wgt);
                ssum = ssum * sc + wgt;
                mx = nmx;
                if (lane == 0) simL[rl] = s;
            }
            if (lane == 0) { smx4[wv] = mx; ssh4[wv] = ssum; }
            __syncthreads();
            float MXb = fmaxf(fmaxf(smx4[0], smx4[1]), fmaxf(smx4[2], smx4[3]));
            float sc2 = __expf(mx - MXb);
            float* d0 = &smacc[wv][lane * 4];
            float* d1 = &smacc[wv][256 + lane * 4];
            d0[0] = macc.a.x * sc2; d0[1] = macc.a.y * sc2;
            d0[2] = macc.a.z * sc2; d0[3] = macc.a.w * sc2;
            d1[0] = macc.b.x * sc2; d1[1] = macc.b.y * sc2;
            d1[2] = macc.b.z * sc2; d1[3] = macc.b.w * sc2;
            __syncthreads();
            for (int r = tid; r < 512; r += 256)
                p.mpart[(size_t)(kb * 8 + w2) * 512 + r] =
                    smacc[0][r] + smacc[1][r] + smacc[2][r] + smacc[3][r];
            if (tid == 0) {
                float sB = ssh4[0] * __expf(smx4[0] - MXb)
                         + ssh4[1] * __expf(smx4[1] - MXb)
                         + ssh4[2] * __expf(smx4[2] - MXb)
                         + ssh4[3] * __expf(smx4[3] - MXb);
                p.mxpart[kb * 8 + w2] = MXb;
                p.sumpart[kb * 8 + w2] = sB;
            }
        }
        // ========= stage A2: read-LSTM gates for t+1 (activations from LDS)
        if (t < 63) {
            f8 A[16]; ldact(A, actH, lane);
            float gv0 = gatedotR(A, wR0, lane);
            float gv1 = gatedotR(A, wR1, lane);
            if ((lane & 3) == 0) {
                int b = (lane >> 2) & 15;
                gsm[0][wv][b] = gv0 + p.pre[(size_t)((t + 1) * 16 + b) * 2048 + jA];
                gsm[1][wv][b] = gv1 + p.pre[(size_t)((t + 1) * 16 + b) * 2048 + jA + 1];
            }
            __syncthreads();
            if (tid < 32) {
                int b = tid & 15, uu = tid >> 4;
                int u = u0 + uu;
                float gi = sigmoidf_(gsm[uu][0][b]);
                float gf = sigmoidf_(gsm[uu][1][b]);
                float gg = tanhf(gsm[uu][2][b]);
                float go = sigmoidf_(gsm[uu][3][b]);
                float c = gf * p.crS[b * 512 + u] + gi * gg;
                p.crS[b * 512 + u] = c;
                hrnext[b * 512 + u] = go * tanhf(c);
            }
        }

        // ========= stage B-lite: group (k,b) softmax stats + mbuf slice
        groupbar(p.bar, kb, (unsigned)(t + 1));
        {
            float MX = -3.0e38f;
            #pragma unroll
            for (int w3 = 0; w3 < 8; ++w3)
                MX = fmaxf(MX, p.mxpart[kb * 8 + w3]);
            float SUM = 0.f;
            #pragma unroll
            for (int w3 = 0; w3 < 8; ++w3)
                SUM += p.sumpart[kb * 8 + w3] * __expf(p.mxpart[kb * 8 + w3] - MX);
            mxK = MX;
            sumInvK = 1.0f / SUM;
            if (tid < 64) {
                int r = w2 * 64 + tid;
                float acc = 0.f;
                #pragma unroll
                for (int w3 = 0; w3 < 8; ++w3)
                    acc += __expf(p.mxpart[kb * 8 + w3] - MX)
                         * p.mpart[(size_t)(kb * 8 + w3) * 512 + r];
                p.mbuf[(size_t)kb * 512 + r] = acc * sumInvK;
            }
        }
        gridbarH(p.bar, ++tg, bid);

        // ========= stage C: comppre GEMV + hoisted vh = hw_prev . Whh_w
        float vh0, vh1;
        {
            f8 H[16]; ldact(H, actW, lane);   // hw_prev from LDS
            vh0 = gatedotR(H, wW0, lane);
            vh1 = gatedotR(H, wW1, lane);
        }
        {
            float v;
            f8 A[16];
            if (part == 0) {
                ldact(A, actH, lane);          // hr from LDS
                v = gatedotR(A, wC0, lane);
                ldact(A, p.mbuf, lane);        // m k=0 (global)
                v += gatedotR(A, wC1, lane);
            } else {
                ldact(A, p.mbuf + 16 * 512, lane);   // m k=1 (global)
                v = gatedotR(A, wC0, lane);
            }
            if ((lane & 3) == 0) {
                int b = (lane >> 2) & 15;
                cc[jj][part][b] = v;
            }
            __syncthreads();
            if (tid < 32) {
                int b = tid & 15, jj2 = tid >> 4;
                p.comppre[b * 512 + (u0 + jj2)] =
                    cc[jj2][0][b] + cc[jj2][1][b] + bcsh[jj2];
            }
        }
        gridbarH(p.bar, ++tg, bid);

        // ========= stage D: cooperative softmax(comppre) -> E in LDS (actH
        // overlay; hr dead after C), then write-LSTM gates from LDS E
        {
            int b = tid >> 4, c0 = (tid & 15) * 32;
            const float4* src = (const float4*)(p.comppre + b * 512 + c0);
            float4 v4[8];
            float mxs = -1e30f;
            #pragma unroll
            for (int q = 0; q < 8; ++q) {
                v4[q] = src[q];
                mxs = fmaxf(mxs, fmaxf(fmaxf(v4[q].x, v4[q].y),
                                       fmaxf(v4[q].z, v4[q].w)));
            }
            #pragma unroll
            for (int d = 1; d < 16; d <<= 1)
                mxs = fmaxf(mxs, __shfl_xor(mxs, d, 64));
            __syncthreads();   // all reads of actH (hr) done before overwrite
            float ss = 0.f;
            float* eb = actH + b * 512 + c0;
            #pragma unroll
            for (int q = 0; q < 8; ++q) {
                float e0 = __expf(v4[q].x - mxs), e1 = __expf(v4[q].y - mxs);
                float e2 = __expf(v4[q].z - mxs), e3 = __expf(v4[q].w - mxs);
                eb[q * 4 + 0] = e0; eb[q * 4 + 1] = e1;
                eb[q * 4 + 2] = e2; eb[q * 4 + 3] = e3;
                ss += e0 + e1 + e2 + e3;
            }
            #pragma unroll
            for (int d = 1; d < 16; d <<= 1) ss += __shfl_xor(ss, d, 64);
            if ((tid & 15) == 0) sinv[b] = 1.0f / ss;
            __syncthreads();

            f8 E[16]; ldact(E, actH, lane);    // unnormalized exp from LDS
            float ti0 = gatedotR(E, wI0, lane);
            float ti1 = gatedotR(E, wI1, lane);
            if ((lane & 3) == 0) {
                int bb = (lane >> 2) & 15;
                gsm[0][wv][bb] = ti0 * sinv[bb] + vh0 + bw0;
                gsm[1][wv][bb] = ti1 * sinv[bb] + vh1 + bw1;
            }
            __syncthreads();
            if (tid < 32) {
                int bb = tid & 15, uu = tid >> 4;
                int u = u0 + uu;
                float gi = sigmoidf_(gsm[uu][0][bb]);
                float gf = sigmoidf_(gsm[uu][1][bb]);
                float gg = tanhf(gsm[uu][2][bb]);
                float go = sigmoidf_(gsm[uu][3][bb]);
                float cprev = (t == 0) ? p.cw0[bb * 512 + u] : p.cwS[bb * 512 + u];
                float c = gf * cprev + gi * gg;
                p.cwS[bb * 512 + u] = c;
                float h = go * tanhf(c);
                hwnext[bb * 512 + u] = h;
                p.outputs[(size_t)t * 8192 + bb * 512 + u] = h;
            }
        }
        gridbarH(p.bar, ++tg, bid);
    }

    // ---- epilogue: final deferred M update with (z_63, hw_63 = hwb1);
    //      write LDS M -> d_out Mf region (the only M global write)
    {
        f8 w8 = ld8s(p.hwb1 + (size_t)bM * 512, lane);
        #pragma unroll
        for (int ii = 0; ii < 8; ++ii) {
            int rl = wv * 8 + ii;
            float zf = 1.0f - __expf(simL[rl] - mxK) * sumInvK;
            f8 m;
            m.a = *(float4*)&Mlds[rl][lane * 4];
            m.b = *(float4*)&Mlds[rl][256 + lane * 4];
            upd8(m, w8, zf);
            st8s(p.Mw + (size_t)(rowG + rl) * 512, m, lane);
        }
    }
}

extern "C" void kernel_launch(void* const* d_in, const int* in_sizes, int n_in,
                              void* d_out, int out_size, void* d_ws, size_t ws_size,
                              hipStream_t stream) {
    const float* emb   = (const float*)d_in[0];
    const float* hr0   = (const float*)d_in[1];
    const float* cr0   = (const float*)d_in[2];
    const float* hw0   = (const float*)d_in[3];
    const float* cw0   = (const float*)d_in[4];
    const float* io    = (const float*)d_in[5];
    const float* M0    = (const float*)d_in[6];
    const float* Wih_r = (const float*)d_in[7];
    const float* bih_r = (const float*)d_in[9];
    const float* bhh_r = (const float*)d_in[10];

    float* out = (float*)d_out;
    float* outputs = out;                    // [64][16][512]
    float* hrS1 = out + 524288;              // hr slot doubles as hr parity-1 buf
    float* crS  = out + 532480;              // cr (in-place state)
    float* hwS1 = out + 540672;              // hw slot doubles as hw parity-1 buf
    float* cwS  = out + 548864;              // cw (in-place state)
    float* Mw   = out + 557056;              // Mf (written once at epilogue)

    float* ws = (float*)d_ws;
    float* pre     = ws;                     // 1024*2048
    float* mbuf    = ws + 2097152;           // 32*512
    float* comppre = mbuf + 16384;           // 16*512
    float* hrB0    = comppre + 8192;         // 8192 (hr parity 0)
    float* hwB0    = hrB0 + 8192;            // 8192 (hw parity 0)
    float* mpart   = hwB0 + 8192;            // 256*512
    float* mxpart  = mpart + 131072;         // 256
    float* sumpart = mxpart + 256;           // 256
    unsigned* bar  = (unsigned*)(sumpart + 256); // 1344 uints

    (void)hipMemsetAsync(bar, 0, 1344 * sizeof(unsigned), stream);

    k_pre<<<dim3(32, 16), 256, 0, stream>>>(emb, io, Wih_r, bih_r, bhh_r, pre);

    P p;
    p.pre = pre;
    p.Whh_r = (const float*)d_in[8];
    p.Wc    = (const float*)d_in[11];
    p.bc    = (const float*)d_in[12];
    p.Wih_w = (const float*)d_in[13];
    p.Whh_w = (const float*)d_in[14];
    p.bih_w = (const float*)d_in[15];
    p.bhh_w = (const float*)d_in[16];
    p.hr0 = hr0; p.cr0 = cr0; p.hw0 = hw0; p.cw0 = cw0; p.M0 = M0;
    p.mbuf = mbuf; p.comppre = comppre;
    p.mpart = mpart; p.mxpart = mxpart; p.sumpart = sumpart;
    p.hrb0 = hrB0; p.hrb1 = hrS1; p.crS = crS;
    p.hwb0 = hwB0; p.hwb1 = hwS1; p.cwS = cwS;
    p.outputs = outputs; p.Mw = Mw;
    p.bar = bar;

    k_persist<<<NBLK, 256, 0, stream>>>(p);
}

// Round 9
// 2969.363 us; speedup vs baseline: 2.1916x; 1.2656x over previous
//
#include <hip/hip_runtime.h>
#include <math.h>

#define RR 512
#define BB 16
#define TT 64
#define KC 2
#define NN 256
#define NBLK 256

__device__ __forceinline__ float sigmoidf_(float x) {
    return 1.0f / (1.0f + __expf(-x));
}
__device__ __forceinline__ float wave_sum(float v) {
    #pragma unroll
    for (int off = 32; off > 0; off >>= 1) v += __shfl_xor(v, off, 64);
    return v;
}
__device__ __forceinline__ float wave_max(float v) {
    #pragma unroll
    for (int off = 32; off > 0; off >>= 1) v = fmaxf(v, __shfl_xor(v, off, 64));
    return v;
}

// ---- relaxed agent-scope word ops: coherent at MALL, NO cache fences ----
__device__ __forceinline__ float ldA(const float* p) {
    return __hip_atomic_load(p, __ATOMIC_RELAXED, __HIP_MEMORY_SCOPE_AGENT);
}
__device__ __forceinline__ void stA(float* p, float v) {
    __hip_atomic_store(p, v, __ATOMIC_RELAXED, __HIP_MEMORY_SCOPE_AGENT);
}

struct f8 { float4 a, b; };
// split-slice mapping: lane's 8 floats of a 512-row = [lane*4,+4) and
// [256+lane*4,+4)  -> contiguous per instruction (LDS conflict-free, global
// coalesced). ALL row slices (weights + activations) use this mapping.
__device__ __forceinline__ f8 ld8s(const float* row, int lane) {
    f8 r;
    r.a = *(const float4*)(row + lane * 4);
    r.b = *(const float4*)(row + 256 + lane * 4);
    return r;
}
__device__ __forceinline__ void st8s(float* row, const f8& v, int lane) {
    *(float4*)(row + lane * 4) = v.a;
    *(float4*)(row + 256 + lane * 4) = v.b;
}
__device__ __forceinline__ f8 ld8sA(const float* row, int lane) {
    f8 r;
    const float* p0 = row + lane * 4;
    const float* p1 = row + 256 + lane * 4;
    r.a.x = ldA(p0 + 0); r.a.y = ldA(p0 + 1); r.a.z = ldA(p0 + 2); r.a.w = ldA(p0 + 3);
    r.b.x = ldA(p1 + 0); r.b.y = ldA(p1 + 1); r.b.z = ldA(p1 + 2); r.b.w = ldA(p1 + 3);
    return r;
}
__device__ __forceinline__ float dot8(const f8& x, const f8& y) {
    return x.a.x*y.a.x + x.a.y*y.a.y + x.a.z*y.a.z + x.a.w*y.a.w
         + x.b.x*y.b.x + x.b.y*y.b.y + x.b.z*y.b.z + x.b.w*y.b.w;
}
// inline function, NOT a macro (macro param `w` collides with float4::w)
__device__ __forceinline__ void upd8(f8& m, const f8& u, float zf) {
    m.a.x = zf * (m.a.x + u.a.x); m.a.y = zf * (m.a.y + u.a.y);
    m.a.z = zf * (m.a.z + u.a.z); m.a.w = zf * (m.a.w + u.a.w);
    m.b.x = zf * (m.b.x + u.b.x); m.b.y = zf * (m.b.y + u.b.y);
    m.b.z = zf * (m.b.z + u.b.z); m.b.w = zf * (m.b.w + u.b.w);
}
__device__ __forceinline__ void fmaacc8(f8& acc, float sc, const f8& m, float wgt) {
    acc.a.x = acc.a.x*sc + wgt*m.a.x; acc.a.y = acc.a.y*sc + wgt*m.a.y;
    acc.a.z = acc.a.z*sc + wgt*m.a.z; acc.a.w = acc.a.w*sc + wgt*m.a.w;
    acc.b.x = acc.b.x*sc + wgt*m.b.x; acc.b.y = acc.b.y*sc + wgt*m.b.y;
    acc.b.z = acc.b.z*sc + wgt*m.b.z; acc.b.w = acc.b.w*sc + wgt*m.b.w;
}

// Payload-halving butterfly: p[0..15] per-b partials across 64 lanes ->
// each lane returns the full sum for b = (lane>>2)&15.
__device__ __forceinline__ float reduce16(float* p, int lane) {
    float q[8];
    {
        bool hi = (lane & 32) != 0;
        #pragma unroll
        for (int i = 0; i < 8; ++i) {
            float snd = hi ? p[i] : p[i + 8];
            float r = __shfl_xor(snd, 32, 64);
            q[i] = (hi ? p[i + 8] : p[i]) + r;
        }
    }
    float s4[4];
    {
        bool hi = (lane & 16) != 0;
        #pragma unroll
        for (int i = 0; i < 4; ++i) {
            float snd = hi ? q[i] : q[i + 4];
            float r = __shfl_xor(snd, 16, 64);
            s4[i] = (hi ? q[i + 4] : q[i]) + r;
        }
    }
    float d2[2];
    {
        bool hi = (lane & 8) != 0;
        #pragma unroll
        for (int i = 0; i < 2; ++i) {
            float snd = hi ? s4[i] : s4[i + 2];
            float r = __shfl_xor(snd, 8, 64);
            d2[i] = (hi ? s4[i + 2] : s4[i]) + r;
        }
    }
    float v;
    {
        bool hi = (lane & 4) != 0;
        float snd = hi ? d2[0] : d2[1];
        float r = __shfl_xor(snd, 4, 64);
        v = (hi ? d2[1] : d2[0]) + r;
    }
    v += __shfl_xor(v, 2, 64);
    v += __shfl_xor(v, 1, 64);
    return v;
}

__device__ __forceinline__ float gatedotR(const f8* A, const f8& w, int lane) {
    float p[16];
    #pragma unroll
    for (int b = 0; b < 16; ++b) p[b] = dot8(A[b], w);
    return reduce16(p, lane);
}
__device__ __forceinline__ void ldacts(f8* A, const float* act, int lane) {
    #pragma unroll
    for (int b = 0; b < 16; ++b) A[b] = ld8s(act + b * 512, lane);
}
__device__ __forceinline__ void ldactsA(f8* A, const float* act, int lane) {
    #pragma unroll
    for (int b = 0; b < 16; ++b) A[b] = ld8sA(act + b * 512, lane);
}

// ---- fence-free hierarchical grid barrier. All atomics RELAXED (no L2
// wb/inv). Ordering: every wave drains vmcnt before syncthreads (explicit +
// compiler); reset->release ordered by vmcnt(0) in thread 0.
__device__ __forceinline__ void gridbarR(unsigned* bar, unsigned tgt, int bid) {
    asm volatile("s_waitcnt vmcnt(0)" ::: "memory");
    __syncthreads();
    if (threadIdx.x == 0) {
        int x = bid & 7;
        unsigned* xcnt = bar + x * 16;
        unsigned* xgen = bar + 128 + x * 16;
        unsigned* mcnt = bar + 256;
        unsigned* mgen = bar + 272;
        unsigned a = __hip_atomic_fetch_add(xcnt, 1u, __ATOMIC_RELAXED,
                                            __HIP_MEMORY_SCOPE_AGENT);
        if (a == 31u) {
            __hip_atomic_store(xcnt, 0u, __ATOMIC_RELAXED, __HIP_MEMORY_SCOPE_AGENT);
            unsigned m = __hip_atomic_fetch_add(mcnt, 1u, __ATOMIC_RELAXED,
                                                __HIP_MEMORY_SCOPE_AGENT);
            if (m == 7u) {
                __hip_atomic_store(mcnt, 0u, __ATOMIC_RELAXED, __HIP_MEMORY_SCOPE_AGENT);
                asm volatile("s_waitcnt vmcnt(0)" ::: "memory");
                __hip_atomic_store(mgen, tgt, __ATOMIC_RELAXED, __HIP_MEMORY_SCOPE_AGENT);
            } else {
                while (__hip_atomic_load(mgen, __ATOMIC_RELAXED,
                                         __HIP_MEMORY_SCOPE_AGENT) < tgt)
                    __builtin_amdgcn_s_sleep(1);
            }
            asm volatile("s_waitcnt vmcnt(0)" ::: "memory");
            __hip_atomic_store(xgen, tgt, __ATOMIC_RELAXED, __HIP_MEMORY_SCOPE_AGENT);
        } else {
            while (__hip_atomic_load(xgen, __ATOMIC_RELAXED,
                                     __HIP_MEMORY_SCOPE_AGENT) < tgt)
                __builtin_amdgcn_s_sleep(1);
        }
    }
    __syncthreads();
}

// fence-free 8-block group barrier for one (k,b) group
__device__ __forceinline__ void groupbar(unsigned* bar, int kb, unsigned tgt) {
    asm volatile("s_waitcnt vmcnt(0)" ::: "memory");
    __syncthreads();
    if (threadIdx.x == 0) {
        unsigned* gcnt = bar + 320 + kb * 16;
        unsigned* ggen = bar + 832 + kb * 16;
        unsigned a = __hip_atomic_fetch_add(gcnt, 1u, __ATOMIC_RELAXED,
                                            __HIP_MEMORY_SCOPE_AGENT);
        if (a == 7u) {
            __hip_atomic_store(gcnt, 0u, __ATOMIC_RELAXED, __HIP_MEMORY_SCOPE_AGENT);
            asm volatile("s_waitcnt vmcnt(0)" ::: "memory");
            __hip_atomic_store(ggen, tgt, __ATOMIC_RELAXED, __HIP_MEMORY_SCOPE_AGENT);
        } else {
            while (__hip_atomic_load(ggen, __ATOMIC_RELAXED,
                                     __HIP_MEMORY_SCOPE_AGENT) < tgt)
                __builtin_amdgcn_s_sleep(1);
        }
    }
    __syncthreads();
}

// ---------------------------------------------------------------------------
// k_pre: pre[t*16+b][j] = [emb|io] @ Wih_r^T + bih_r + bhh_r   (proven r1-r8)
// ---------------------------------------------------------------------------
__global__ void k_pre(const float* __restrict__ emb, const float* __restrict__ io,
                      const float* __restrict__ Wih, const float* __restrict__ bih,
                      const float* __restrict__ bhh, float* __restrict__ pre)
{
    __shared__ float As[16][65];
    __shared__ float Bs[16][65];
    int tid = threadIdx.x;
    int row0 = blockIdx.y * 64;
    int col0 = blockIdx.x * 64;
    int ty = tid >> 4, tx = tid & 15;
    float acc[4][4] = {};
    int lr = tid >> 2;
    int lk4 = (tid & 3) * 4;
    for (int k0 = 0; k0 < 1024; k0 += 16) {
        int grow = row0 + lr;
        int b = grow & 15;
        #pragma unroll
        for (int q = 0; q < 4; ++q) {
            int k = k0 + lk4 + q;
            float v = (k < RR) ? emb[(size_t)grow * RR + k]
                               : io[(size_t)b * RR + (k - RR)];
            As[lk4 + q][lr] = v;
        }
        #pragma unroll
        for (int q = 0; q < 4; ++q) {
            int k = k0 + lk4 + q;
            Bs[lk4 + q][lr] = Wih[(size_t)(col0 + lr) * 1024 + k];
        }
        __syncthreads();
        #pragma unroll
        for (int kk = 0; kk < 16; ++kk) {
            float a[4], bbv[4];
            #pragma unroll
            for (int i = 0; i < 4; ++i) a[i] = As[kk][ty * 4 + i];
            #pragma unroll
            for (int j = 0; j < 4; ++j) bbv[j] = Bs[kk][tx * 4 + j];
            #pragma unroll
            for (int i = 0; i < 4; ++i)
                #pragma unroll
                for (int j = 0; j < 4; ++j)
                    acc[i][j] += a[i] * bbv[j];
        }
        __syncthreads();
    }
    #pragma unroll
    for (int i = 0; i < 4; ++i) {
        int grow = row0 + ty * 4 + i;
        #pragma unroll
        for (int j = 0; j < 4; ++j) {
            int gcol = col0 + tx * 4 + j;
            pre[(size_t)grow * 2048 + gcol] = acc[i][j] + bih[gcol] + bhh[gcol];
        }
    }
}

struct P {
    const float *pre, *Whh_r, *Wc, *bc, *Wih_w, *Whh_w, *bih_w, *bhh_w;
    const float *hr0, *cr0, *hw0, *cw0, *M0;
    float *mbuf, *comppre, *mpart, *mxpart, *sumpart;
    float *hrb0, *hrb1, *crS, *hwb0, *hwb1, *cwS;
    float *outputs, *Mw;
    unsigned *bar;
};

// ---------------------------------------------------------------------------
// Persistent kernel: 64-step recurrence. M + staged activations in LDS;
// weights + cr/cw in registers; fence-free barriers; all cross-block data on
// relaxed device-scope atomics.
// ---------------------------------------------------------------------------
__global__ void __launch_bounds__(256, 1) k_persist(P p)
{
    const int tid = threadIdx.x;
    const int bid = blockIdx.x;
    const int wv = tid >> 6;
    const int lane = tid & 63;
    const int u0 = bid * 2;
    const int kb = (bid & 7) * 4 + (bid >> 6);   // (k,b) group
    const int w2 = (bid >> 3) & 7;               // slot within group
    const int bM = kb & 15;
    const int rowG = kb * 256 + w2 * 32;

    __shared__ float Mlds[32][512];       // 64 KB
    __shared__ float actH[16 * 512];      // 32 KB: hr_t staged; E overlay in D
    __shared__ float actW[16 * 512];      // 32 KB: hw_{t-1} staged
    __shared__ float smacc[4][512];       // 8 KB
    __shared__ float smx4[4], ssh4[4];
    __shared__ float simL[32];
    __shared__ float gsm[2][4][16];
    __shared__ float cc[2][2][16];
    __shared__ float wmx[16][2], wsm[16][2];
    __shared__ float bcsh[2];

    unsigned tg = 0;
    float mxK = 0.f, sumInvK = 0.f;
    float crR = 0.f, cwR = 0.f;           // cr/cw state (tid<32 threads own it)

    // ---- register-resident weight slices (split-slice mapping)
    const int jA = wv * 512 + u0;
    const f8 wR0 = ld8s(p.Whh_r + (size_t)jA * 512, lane);
    const f8 wR1 = ld8s(p.Whh_r + (size_t)(jA + 1) * 512, lane);
    const f8 wW0 = ld8s(p.Whh_w + (size_t)jA * 512, lane);
    const f8 wW1 = ld8s(p.Whh_w + (size_t)(jA + 1) * 512, lane);
    const f8 wI0 = ld8s(p.Wih_w + (size_t)jA * 512, lane);
    const f8 wI1 = ld8s(p.Wih_w + (size_t)(jA + 1) * 512, lane);
    const float bw0 = p.bih_w[jA] + p.bhh_w[jA];
    const float bw1 = p.bih_w[jA + 1] + p.bhh_w[jA + 1];
    const int jj = wv >> 1, part = wv & 1;
    const int jC = u0 + jj;
    f8 wC0, wC1 = {};
    if (part == 0) {
        wC0 = ld8s(p.Wc + (size_t)jC * 1536, lane);
        wC1 = ld8s(p.Wc + (size_t)jC * 1536 + 512, lane);
    } else {
        wC0 = ld8s(p.Wc + (size_t)jC * 1536 + 1024, lane);
    }
    if (tid < 2) bcsh[tid] = p.bc[u0 + tid];
    if (tid < 32) cwR = p.cw0[(tid & 15) * 512 + u0 + (tid >> 4)];

    // ---- load this block's M rows: global M0 -> LDS (once)
    {
        const float4* src = (const float4*)(p.M0 + (size_t)rowG * 512);
        float4* dst = (float4*)&Mlds[0][0];
        #pragma unroll 4
        for (int idx = tid; idx < 32 * 128; idx += 256)
            dst[idx] = src[idx];
    }

    // ---- prologue: read-LSTM step 0 -> hr_0 (hrb0, atomic), cr_0 (register)
    {
        f8 A[16]; ldacts(A, p.hr0, lane);
        float gv0 = gatedotR(A, wR0, lane);
        float gv1 = gatedotR(A, wR1, lane);
        if ((lane & 3) == 0) {
            int b = (lane >> 2) & 15;
            gsm[0][wv][b] = gv0 + p.pre[(size_t)b * 2048 + jA];
            gsm[1][wv][b] = gv1 + p.pre[(size_t)b * 2048 + jA + 1];
        }
        __syncthreads();
        if (tid < 32) {
            int b = tid & 15, uu = tid >> 4;
            int u = u0 + uu;
            float gi = sigmoidf_(gsm[uu][0][b]);
            float gf = sigmoidf_(gsm[uu][1][b]);
            float gg = tanhf(gsm[uu][2][b]);
            float go = sigmoidf_(gsm[uu][3][b]);
            float c = gf * p.cr0[b * 512 + u] + gi * gg;
            crR = c;
            stA(p.hrb0 + b * 512 + u, go * tanhf(c));
        }
        gridbarR(p.bar, ++tg, bid);
    }

    for (int t = 0; t < TT; ++t) {
        const float* hrcur  = (t & 1) ? p.hrb1 : p.hrb0;
        float*       hrnext = (t & 1) ? p.hrb0 : p.hrb1;
        const float* hwprev = (t == 0) ? p.hw0 : (((t - 1) & 1) ? p.hwb1 : p.hwb0);
        float*       hwnext = (t & 1) ? p.hwb1 : p.hwb0;

        // ---- stage hr_t and hw_{t-1} into LDS via relaxed atomic loads
        {
            #pragma unroll
            for (int q = 0; q < 8; ++q) {
                int idx = q * 1024 + tid * 4;
                float4 a4, b4;
                a4.x = ldA(hrcur + idx);     a4.y = ldA(hrcur + idx + 1);
                a4.z = ldA(hrcur + idx + 2); a4.w = ldA(hrcur + idx + 3);
                b4.x = ldA(hwprev + idx);     b4.y = ldA(hwprev + idx + 1);
                b4.z = ldA(hwprev + idx + 2); b4.w = ldA(hwprev + idx + 3);
                ((float4*)actH)[q * 256 + tid] = a4;
                ((float4*)actW)[q * 256 + tid] = b4;
            }
        }
        __syncthreads();

        // ========= stage A: deferred M update (local z) + sim + online partials
        {
            f8 h = ld8s(actH + bM * 512, lane);
            f8 w8 = {};
            if (t > 0) w8 = ld8s(actW + bM * 512, lane);
            float mx = -3.0e38f, ssum = 0.f;
            f8 macc = {};
            #pragma unroll
            for (int ii = 0; ii < 8; ++ii) {
                int rl = wv * 8 + ii;
                float4* mp0 = (float4*)&Mlds[rl][lane * 4];
                float4* mp1 = (float4*)&Mlds[rl][256 + lane * 4];
                f8 m; m.a = *mp0; m.b = *mp1;
                if (t > 0) {
                    float zf = 1.0f - __expf(simL[rl] - mxK) * sumInvK;
                    upd8(m, w8, zf);
                    *mp0 = m.a; *mp1 = m.b;
                }
                float s = wave_sum(dot8(m, h));
                float nmx = fmaxf(mx, s);
                float sc = __expf(mx - nmx);
                float wgt = __expf(s - nmx);
                fmaacc8(macc, sc, m, wgt);
                ssum = ssum * sc + wgt;
                mx = nmx;
                if (lane == 0) simL[rl] = s;
            }
            if (lane == 0) { smx4[wv] = mx; ssh4[wv] = ssum; }
            __syncthreads();
            float MXb = fmaxf(fmaxf(smx4[0], smx4[1]), fmaxf(smx4[2], smx4[3]));
            float sc2 = __expf(mx - MXb);
            float* d0 = &smacc[wv][lane * 4];
            float* d1 = &smacc[wv][256 + lane * 4];
            d0[0] = macc.a.x * sc2; d0[1] = macc.a.y * sc2;
            d0[2] = macc.a.z * sc2; d0[3] = macc.a.w * sc2;
            d1[0] = macc.b.x * sc2; d1[1] = macc.b.y * sc2;
            d1[2] = macc.b.z * sc2; d1[3] = macc.b.w * sc2;
            __syncthreads();
            for (int r = tid; r < 512; r += 256)
                stA(&p.mpart[(size_t)(kb * 8 + w2) * 512 + r],
                    smacc[0][r] + smacc[1][r] + smacc[2][r] + smacc[3][r]);
            if (tid == 0) {
                float sB = ssh4[0] * __expf(smx4[0] - MXb)
                         + ssh4[1] * __expf(smx4[1] - MXb)
                         + ssh4[2] * __expf(smx4[2] - MXb)
                         + ssh4[3] * __expf(smx4[3] - MXb);
                stA(&p.mxpart[kb * 8 + w2], MXb);
                stA(&p.sumpart[kb * 8 + w2], sB);
            }
        }
        // ========= stage A2: read-LSTM gates for t+1 (LDS activations)
        if (t < 63) {
            f8 A[16]; ldacts(A, actH, lane);
            float gv0 = gatedotR(A, wR0, lane);
            float gv1 = gatedotR(A, wR1, lane);
            if ((lane & 3) == 0) {
                int b = (lane >> 2) & 15;
                gsm[0][wv][b] = gv0 + p.pre[(size_t)((t + 1) * 16 + b) * 2048 + jA];
                gsm[1][wv][b] = gv1 + p.pre[(size_t)((t + 1) * 16 + b) * 2048 + jA + 1];
            }
            __syncthreads();
            if (tid < 32) {
                int b = tid & 15, uu = tid >> 4;
                int u = u0 + uu;
                float gi = sigmoidf_(gsm[uu][0][b]);
                float gf = sigmoidf_(gsm[uu][1][b]);
                float gg = tanhf(gsm[uu][2][b]);
                float go = sigmoidf_(gsm[uu][3][b]);
                float c = gf * crR + gi * gg;
                crR = c;
                stA(hrnext + b * 512 + u, go * tanhf(c));
            }
        }

        // ========= stage B-lite: group (k,b) softmax stats + mbuf slice
        groupbar(p.bar, kb, (unsigned)(t + 1));
        {
            float mxp[8];
            #pragma unroll
            for (int w3 = 0; w3 < 8; ++w3) mxp[w3] = ldA(&p.mxpart[kb * 8 + w3]);
            float MX = -3.0e38f;
            #pragma unroll
            for (int w3 = 0; w3 < 8; ++w3) MX = fmaxf(MX, mxp[w3]);
            float SUM = 0.f;
            #pragma unroll
            for (int w3 = 0; w3 < 8; ++w3)
                SUM += ldA(&p.sumpart[kb * 8 + w3]) * __expf(mxp[w3] - MX);
            mxK = MX;
            sumInvK = 1.0f / SUM;
            if (tid < 64) {
                int r = w2 * 64 + tid;
                float acc = 0.f;
                #pragma unroll
                for (int w3 = 0; w3 < 8; ++w3)
                    acc += __expf(mxp[w3] - MX)
                         * ldA(&p.mpart[(size_t)(kb * 8 + w3) * 512 + r]);
                stA(&p.mbuf[(size_t)kb * 512 + r], acc * sumInvK);
            }
        }
        gridbarR(p.bar, ++tg, bid);

        // ========= stage C: comppre GEMV + hoisted vh = hw_prev . Whh_w
        float vh0, vh1;
        {
            f8 H[16]; ldacts(H, actW, lane);
            vh0 = gatedotR(H, wW0, lane);
            vh1 = gatedotR(H, wW1, lane);
        }
        {
            float v;
            f8 A[16];
            if (part == 0) {
                ldacts(A, actH, lane);
                v = gatedotR(A, wC0, lane);
                ldactsA(A, p.mbuf, lane);
                v += gatedotR(A, wC1, lane);
            } else {
                ldactsA(A, p.mbuf + 16 * 512, lane);
                v = gatedotR(A, wC0, lane);
            }
            if ((lane & 3) == 0) {
                int b = (lane >> 2) & 15;
                cc[jj][part][b] = v;
            }
            __syncthreads();
            if (tid < 32) {
                int b = tid & 15, jj2 = tid >> 4;
                stA(&p.comppre[b * 512 + (u0 + jj2)],
                    cc[jj2][0][b] + cc[jj2][1][b] + bcsh[jj2]);
            }
        }
        gridbarR(p.bar, ++tg, bid);

        // ========= stage D: cooperative softmax -> E (coalesced, conflict-
        // free) in actH overlay; write-LSTM gates from LDS E
        {
            float v[8][4];
            #pragma unroll
            for (int k = 0; k < 8; ++k) {
                int idx = k * 1024 + tid * 4;
                #pragma unroll
                for (int j = 0; j < 4; ++j) v[k][j] = ldA(p.comppre + idx + j);
            }
            const int bpar = wv >> 1;     // tid>>7
            #pragma unroll
            for (int k = 0; k < 8; ++k) {
                float mk = fmaxf(fmaxf(v[k][0], v[k][1]), fmaxf(v[k][2], v[k][3]));
                mk = wave_max(mk);
                if (lane == 0) wmx[2 * k + bpar][wv & 1] = mk;
            }
            __syncthreads();                 // also: actH (hr) reads all done
            float4* Eld4 = (float4*)actH;
            #pragma unroll
            for (int k = 0; k < 8; ++k) {
                float mxb = fmaxf(wmx[2 * k + bpar][0], wmx[2 * k + bpar][1]);
                float e0 = __expf(v[k][0] - mxb), e1 = __expf(v[k][1] - mxb);
                float e2 = __expf(v[k][2] - mxb), e3 = __expf(v[k][3] - mxb);
                Eld4[k * 256 + tid] = make_float4(e0, e1, e2, e3);
                float sv = wave_sum(e0 + e1 + e2 + e3);
                if (lane == 0) wsm[2 * k + bpar][wv & 1] = sv;
            }
            __syncthreads();
            f8 E[16]; ldacts(E, actH, lane);
            float ti0 = gatedotR(E, wI0, lane);
            float ti1 = gatedotR(E, wI1, lane);
            if ((lane & 3) == 0) {
                int bb = (lane >> 2) & 15;
                float siv = 1.0f / (wsm[bb][0] + wsm[bb][1]);
                gsm[0][wv][bb] = ti0 * siv + vh0 + bw0;
                gsm[1][wv][bb] = ti1 * siv + vh1 + bw1;
            }
            __syncthreads();
            if (tid < 32) {
                int bb = tid & 15, uu = tid >> 4;
                int u = u0 + uu;
                float gi = sigmoidf_(gsm[uu][0][bb]);
                float gf = sigmoidf_(gsm[uu][1][bb]);
                float gg = tanhf(gsm[uu][2][bb]);
                float go = sigmoidf_(gsm[uu][3][bb]);
                float c = gf * cwR + gi * gg;
                cwR = c;
                float h = go * tanhf(c);
                stA(hwnext + bb * 512 + u, h);
                p.outputs[(size_t)t * 8192 + bb * 512 + u] = h;
            }
        }
        gridbarR(p.bar, ++tg, bid);
    }

    // ---- epilogue: final deferred M update with (z_63, hw_63 = hwb1);
    //      write LDS M -> Mf; flush cr/cw registers to d_out
    {
        f8 w8 = ld8sA(p.hwb1 + (size_t)bM * 512, lane);
        #pragma unroll
        for (int ii = 0; ii < 8; ++ii) {
            int rl = wv * 8 + ii;
            float zf = 1.0f - __expf(simL[rl] - mxK) * sumInvK;
            f8 m;
            m.a = *(float4*)&Mlds[rl][lane * 4];
            m.b = *(float4*)&Mlds[rl][256 + lane * 4];
            upd8(m, w8, zf);
            st8s(p.Mw + (size_t)(rowG + rl) * 512, m, lane);
        }
        if (tid < 32) {
            int b = tid & 15, uu = tid >> 4;
            int u = u0 + uu;
            p.crS[b * 512 + u] = crR;
            p.cwS[b * 512 + u] = cwR;
        }
    }
}

extern "C" void kernel_launch(void* const* d_in, const int* in_sizes, int n_in,
                              void* d_out, int out_size, void* d_ws, size_t ws_size,
                              hipStream_t stream) {
    const float* emb   = (const float*)d_in[0];
    const float* hr0   = (const float*)d_in[1];
    const float* cr0   = (const float*)d_in[2];
    const float* hw0   = (const float*)d_in[3];
    const float* cw0   = (const float*)d_in[4];
    const float* io    = (const float*)d_in[5];
    const float* M0    = (const float*)d_in[6];
    const float* Wih_r = (const float*)d_in[7];
    const float* bih_r = (const float*)d_in[9];
    const float* bhh_r = (const float*)d_in[10];

    float* out = (float*)d_out;
    float* outputs = out;                    // [64][16][512]
    float* hrS1 = out + 524288;              // hr slot = hr parity-1 buf
    float* crS  = out + 532480;
    float* hwS1 = out + 540672;              // hw slot = hw parity-1 buf
    float* cwS  = out + 548864;
    float* Mw   = out + 557056;              // Mf (written once at epilogue)

    float* ws = (float*)d_ws;
    float* pre     = ws;                     // 1024*2048
    float* mbuf    = ws + 2097152;           // 32*512
    float* comppre = mbuf + 16384;           // 16*512
    float* hrB0    = comppre + 8192;         // hr parity 0
    float* hwB0    = hrB0 + 8192;            // hw parity 0
    float* mpart   = hwB0 + 8192;            // 256*512
    float* mxpart  = mpart + 131072;         // 256
    float* sumpart = mxpart + 256;           // 256
    unsigned* bar  = (unsigned*)(sumpart + 256); // 1344 uints

    (void)hipMemsetAsync(bar, 0, 1344 * sizeof(unsigned), stream);

    k_pre<<<dim3(32, 16), 256, 0, stream>>>(emb, io, Wih_r, bih_r, bhh_r, pre);

    P p;
    p.pre = pre;
    p.Whh_r = (const float*)d_in[8];
    p.Wc    = (const float*)d_in[11];
    p.bc    = (const float*)d_in[12];
    p.Wih_w = (const float*)d_in[13];
    p.Whh_w = (const float*)d_in[14];
    p.bih_w = (const float*)d_in[15];
    p.bhh_w = (const float*)d_in[16];
    p.hr0 = hr0; p.cr0 = cr0; p.hw0 = hw0; p.cw0 = cw0; p.M0 = M0;
    p.mbuf = mbuf; p.comppre = comppre;
    p.mpart = mpart; p.mxpart = mxpart; p.sumpart = sumpart;
    p.hrb0 = hrB0; p.hrb1 = hrS1; p.crS = crS;
    p.hwb0 = hwB0; p.hwb1 = hwS1; p.cwS = cwS;
    p.outputs = outputs; p.Mw = Mw;
    p.bar = bar;

    k_persist<<<NBLK, 256, 0, stream>>>(p);
}

// Round 11
// 2828.001 us; speedup vs baseline: 2.3012x; 1.0500x over previous
//
#include <hip/hip_runtime.h>
#include <math.h>

#define RR 512
#define BB 16
#define TT 64
#define KC 2
#define NN 256
#define NBLK 256

__device__ __forceinline__ float sigmoidf_(float x) {
    return 1.0f / (1.0f + __expf(-x));
}
__device__ __forceinline__ float wave_sum(float v) {
    #pragma unroll
    for (int off = 32; off > 0; off >>= 1) v += __shfl_xor(v, off, 64);
    return v;
}
__device__ __forceinline__ float wave_max(float v) {
    #pragma unroll
    for (int off = 32; off > 0; off >>= 1) v = fmaxf(v, __shfl_xor(v, off, 64));
    return v;
}

// ---- relaxed agent-scope word ops (MALL-coherent, no cache fences) ----
__device__ __forceinline__ float ldA(const float* p) {
    return __hip_atomic_load(p, __ATOMIC_RELAXED, __HIP_MEMORY_SCOPE_AGENT);
}
__device__ __forceinline__ void stA(float* p, float v) {
    __hip_atomic_store(p, v, __ATOMIC_RELAXED, __HIP_MEMORY_SCOPE_AGENT);
}
__device__ __forceinline__ unsigned ldU(const unsigned* p) {
    return __hip_atomic_load(p, __ATOMIC_RELAXED, __HIP_MEMORY_SCOPE_AGENT);
}
__device__ __forceinline__ void stU(unsigned* p, unsigned v) {
    __hip_atomic_store(p, v, __ATOMIC_RELAXED, __HIP_MEMORY_SCOPE_AGENT);
}

struct f8 { float4 a, b; };
// split-slice mapping: lane's 8 floats of a 512-row = [lane*4,+4) and
// [256+lane*4,+4). Conflict-free LDS b128 + coalesced global.
__device__ __forceinline__ f8 ld8s(const float* row, int lane) {
    f8 r;
    r.a = *(const float4*)(row + lane * 4);
    r.b = *(const float4*)(row + 256 + lane * 4);
    return r;
}
__device__ __forceinline__ void st8s(float* row, const f8& v, int lane) {
    *(float4*)(row + lane * 4) = v.a;
    *(float4*)(row + 256 + lane * 4) = v.b;
}
__device__ __forceinline__ f8 ld8sA(const float* row, int lane) {
    f8 r;
    const float* p0 = row + lane * 4;
    const float* p1 = row + 256 + lane * 4;
    r.a.x = ldA(p0 + 0); r.a.y = ldA(p0 + 1); r.a.z = ldA(p0 + 2); r.a.w = ldA(p0 + 3);
    r.b.x = ldA(p1 + 0); r.b.y = ldA(p1 + 1); r.b.z = ldA(p1 + 2); r.b.w = ldA(p1 + 3);
    return r;
}
__device__ __forceinline__ float dot8(const f8& x, const f8& y) {
    return x.a.x*y.a.x + x.a.y*y.a.y + x.a.z*y.a.z + x.a.w*y.a.w
         + x.b.x*y.b.x + x.b.y*y.b.y + x.b.z*y.b.z + x.b.w*y.b.w;
}
// inline function, NOT a macro (macro param `w` collides with float4::w)
__device__ __forceinline__ void upd8(f8& m, const f8& u, float zf) {
    m.a.x = zf * (m.a.x + u.a.x); m.a.y = zf * (m.a.y + u.a.y);
    m.a.z = zf * (m.a.z + u.a.z); m.a.w = zf * (m.a.w + u.a.w);
    m.b.x = zf * (m.b.x + u.b.x); m.b.y = zf * (m.b.y + u.b.y);
    m.b.z = zf * (m.b.z + u.b.z); m.b.w = zf * (m.b.w + u.b.w);
}
__device__ __forceinline__ void fmaacc8(f8& acc, float sc, const f8& m, float wgt) {
    acc.a.x = acc.a.x*sc + wgt*m.a.x; acc.a.y = acc.a.y*sc + wgt*m.a.y;
    acc.a.z = acc.a.z*sc + wgt*m.a.z; acc.a.w = acc.a.w*sc + wgt*m.a.w;
    acc.b.x = acc.b.x*sc + wgt*m.b.x; acc.b.y = acc.b.y*sc + wgt*m.b.y;
    acc.b.z = acc.b.z*sc + wgt*m.b.z; acc.b.w = acc.b.w*sc + wgt*m.b.w;
}

// Payload-halving butterfly: p[0..15] per-b partials across 64 lanes ->
// each lane returns the full sum for b = (lane>>2)&15.
__device__ __forceinline__ float reduce16(float* p, int lane) {
    float q[8];
    {
        bool hi = (lane & 32) != 0;
        #pragma unroll
        for (int i = 0; i < 8; ++i) {
            float snd = hi ? p[i] : p[i + 8];
            float r = __shfl_xor(snd, 32, 64);
            q[i] = (hi ? p[i + 8] : p[i]) + r;
        }
    }
    float s4[4];
    {
        bool hi = (lane & 16) != 0;
        #pragma unroll
        for (int i = 0; i < 4; ++i) {
            float snd = hi ? q[i] : q[i + 4];
            float r = __shfl_xor(snd, 16, 64);
            s4[i] = (hi ? q[i + 4] : q[i]) + r;
        }
    }
    float d2[2];
    {
        bool hi = (lane & 8) != 0;
        #pragma unroll
        for (int i = 0; i < 2; ++i) {
            float snd = hi ? s4[i] : s4[i + 2];
            float r = __shfl_xor(snd, 8, 64);
            d2[i] = (hi ? s4[i + 2] : s4[i]) + r;
        }
    }
    float v;
    {
        bool hi = (lane & 4) != 0;
        float snd = hi ? d2[0] : d2[1];
        float r = __shfl_xor(snd, 4, 64);
        v = (hi ? d2[1] : d2[0]) + r;
    }
    v += __shfl_xor(v, 2, 64);
    v += __shfl_xor(v, 1, 64);
    return v;
}

__device__ __forceinline__ float gatedotR(const f8* A, const f8& w, int lane) {
    float p[16];
    #pragma unroll
    for (int b = 0; b < 16; ++b) p[b] = dot8(A[b], w);
    return reduce16(p, lane);
}
// gatedot streaming rows from LDS (low register pressure, block-local)
__device__ __forceinline__ float gatedotL(const float* act, const f8& w, int lane) {
    float p[16];
    #pragma unroll
    for (int b = 0; b < 16; ++b) {
        f8 r = ld8s(act + b * 512, lane);
        p[b] = dot8(r, w);
    }
    return reduce16(p, lane);
}
__device__ __forceinline__ void ldacts(f8* A, const float* act, int lane) {
    #pragma unroll
    for (int b = 0; b < 16; ++b) A[b] = ld8s(act + b * 512, lane);
}
__device__ __forceinline__ void ldactsA(f8* A, const float* act, int lane) {
    #pragma unroll
    for (int b = 0; b < 16; ++b) A[b] = ld8sA(act + b * 512, lane);
}

// ---- store-slot barrier (RMW-free, fence-free). slots[256] hold each
// block's monotonically increasing generation. Arrival = per-wave vmcnt
// drain -> syncthreads -> one relaxed store. Wait = wave-0 lanes poll until
// __all(slot >= tgt). No release hop, no counter reset, no ABA (monotone).
__device__ __forceinline__ void barArrive(unsigned* slots, int sidx, unsigned tgt) {
    asm volatile("s_waitcnt vmcnt(0)" ::: "memory");
    __syncthreads();
    if (threadIdx.x == 0) stU(slots + sidx, tgt);
}
__device__ __forceinline__ void gridWait(unsigned* slots, unsigned tgt) {
    if (threadIdx.x < 64) {
        const unsigned* base = slots + threadIdx.x * 4;
        for (;;) {
            bool ok = (ldU(base + 0) >= tgt) & (ldU(base + 1) >= tgt)
                    & (ldU(base + 2) >= tgt) & (ldU(base + 3) >= tgt);
            if (__all(ok)) break;
            __builtin_amdgcn_s_sleep(1);
        }
    }
    __syncthreads();
}
__device__ __forceinline__ void groupWait(unsigned* slots, int gbase, unsigned tgt) {
    if (threadIdx.x < 64) {
        const unsigned* ps = slots + gbase + (threadIdx.x & 7);
        for (;;) {
            bool ok = ldU(ps) >= tgt;
            if (__all(ok)) break;
            __builtin_amdgcn_s_sleep(1);
        }
    }
    __syncthreads();
}

// ---------------------------------------------------------------------------
// k_pre: pre[t*16+b][j] = [emb|io] @ Wih_r^T + bih_r + bhh_r   (proven r1-r9)
// ---------------------------------------------------------------------------
__global__ void k_pre(const float* __restrict__ emb, const float* __restrict__ io,
                      const float* __restrict__ Wih, const float* __restrict__ bih,
                      const float* __restrict__ bhh, float* __restrict__ pre)
{
    __shared__ float As[16][65];
    __shared__ float Bs[16][65];
    int tid = threadIdx.x;
    int row0 = blockIdx.y * 64;
    int col0 = blockIdx.x * 64;
    int ty = tid >> 4, tx = tid & 15;
    float acc[4][4] = {};
    int lr = tid >> 2;
    int lk4 = (tid & 3) * 4;
    for (int k0 = 0; k0 < 1024; k0 += 16) {
        int grow = row0 + lr;
        int b = grow & 15;
        #pragma unroll
        for (int q = 0; q < 4; ++q) {
            int k = k0 + lk4 + q;
            float v = (k < RR) ? emb[(size_t)grow * RR + k]
                               : io[(size_t)b * RR + (k - RR)];
            As[lk4 + q][lr] = v;
        }
        #pragma unroll
        for (int q = 0; q < 4; ++q) {
            int k = k0 + lk4 + q;
            Bs[lk4 + q][lr] = Wih[(size_t)(col0 + lr) * 1024 + k];
        }
        __syncthreads();
        #pragma unroll
        for (int kk = 0; kk < 16; ++kk) {
            float a[4], bbv[4];
            #pragma unroll
            for (int i = 0; i < 4; ++i) a[i] = As[kk][ty * 4 + i];
            #pragma unroll
            for (int j = 0; j < 4; ++j) bbv[j] = Bs[kk][tx * 4 + j];
            #pragma unroll
            for (int i = 0; i < 4; ++i)
                #pragma unroll
                for (int j = 0; j < 4; ++j)
                    acc[i][j] += a[i] * bbv[j];
        }
        __syncthreads();
    }
    #pragma unroll
    for (int i = 0; i < 4; ++i) {
        int grow = row0 + ty * 4 + i;
        #pragma unroll
        for (int j = 0; j < 4; ++j) {
            int gcol = col0 + tx * 4 + j;
            pre[(size_t)grow * 2048 + gcol] = acc[i][j] + bih[gcol] + bhh[gcol];
        }
    }
}

struct P {
    const float *pre, *Whh_r, *Wc, *bc, *Wih_w, *Whh_w, *bih_w, *bhh_w;
    const float *hr0, *cr0, *hw0, *cw0, *M0;
    float *mbuf, *comppre, *mpart, *mxpart, *sumpart;
    float *hrb0, *hrb1, *crS, *hwb0, *hwb1, *cwS;
    float *outputs, *Mw;
    unsigned *slots;
};

// ---------------------------------------------------------------------------
// Persistent kernel: 64-step recurrence. M + staged activations in LDS;
// weights + cr/cw in registers; store-slot barriers; cross-block data via
// relaxed agent-scope word atomics (r9-proven pattern).
// ---------------------------------------------------------------------------
__global__ void __launch_bounds__(256, 1) k_persist(P p)
{
    const int tid = threadIdx.x;
    const int bid = blockIdx.x;
    const int wv = tid >> 6;
    const int lane = tid & 63;
    const int u0 = bid * 2;
    const int kb = (bid & 7) * 4 + (bid >> 6);   // (k,b) group
    const int w2 = (bid >> 3) & 7;               // slot within group
    const int bM = kb & 15;
    const int rowG = kb * 256 + w2 * 32;
    const int sidx = kb * 8 + w2;                // barrier slot (group-contig)
    const int gbase = kb * 8;

    __shared__ float Mlds[32][512];       // 64 KB
    __shared__ float actH[16 * 512];      // 32 KB: hr_t staged; E overlay in D
    __shared__ float actW[16 * 512];      // 32 KB: hw_{t-1} staged
    __shared__ float smacc[4][512];       // 8 KB
    __shared__ float smx4[4], ssh4[4];
    __shared__ float simL[32];
    __shared__ float gsm[2][4][16];
    __shared__ float cc[2][2][16];
    __shared__ float wmx[16][2], wsm[16][2];
    __shared__ float bcsh[2];

    unsigned tg = 0;
    float mxK = 0.f, sumInvK = 0.f;
    float crR = 0.f, cwR = 0.f;

    // ---- register-resident weight slices (split-slice mapping)
    const int jA = wv * 512 + u0;
    const f8 wR0 = ld8s(p.Whh_r + (size_t)jA * 512, lane);
    const f8 wR1 = ld8s(p.Whh_r + (size_t)(jA + 1) * 512, lane);
    const f8 wW0 = ld8s(p.Whh_w + (size_t)jA * 512, lane);
    const f8 wW1 = ld8s(p.Whh_w + (size_t)(jA + 1) * 512, lane);
    const f8 wI0 = ld8s(p.Wih_w + (size_t)jA * 512, lane);
    const f8 wI1 = ld8s(p.Wih_w + (size_t)(jA + 1) * 512, lane);
    const float bw0 = p.bih_w[jA] + p.bhh_w[jA];
    const float bw1 = p.bih_w[jA + 1] + p.bhh_w[jA + 1];
    const int jj = wv >> 1, part = wv & 1;
    const int jC = u0 + jj;
    f8 wC0, wC1 = {};
    if (part == 0) {
        wC0 = ld8s(p.Wc + (size_t)jC * 1536, lane);
        wC1 = ld8s(p.Wc + (size_t)jC * 1536 + 512, lane);
    } else {
        wC0 = ld8s(p.Wc + (size_t)jC * 1536 + 1024, lane);
    }
    if (tid < 2) bcsh[tid] = p.bc[u0 + tid];
    if (tid < 32) cwR = p.cw0[(tid & 15) * 512 + u0 + (tid >> 4)];

    // ---- load this block's M rows: global M0 -> LDS (once)
    {
        const float4* src = (const float4*)(p.M0 + (size_t)rowG * 512);
        float4* dst = (float4*)&Mlds[0][0];
        #pragma unroll 4
        for (int idx = tid; idx < 32 * 128; idx += 256)
            dst[idx] = src[idx];
    }

    // ---- prologue: read-LSTM step 0 -> hr_0 (hrb0), cr_0 (register)
    {
        f8 A[16]; ldacts(A, p.hr0, lane);
        float gv0 = gatedotR(A, wR0, lane);
        float gv1 = gatedotR(A, wR1, lane);
        if ((lane & 3) == 0) {
            int b = (lane >> 2) & 15;
            gsm[0][wv][b] = gv0 + p.pre[(size_t)b * 2048 + jA];
            gsm[1][wv][b] = gv1 + p.pre[(size_t)b * 2048 + jA + 1];
        }
        __syncthreads();
        if (tid < 32) {
            int b = tid & 15, uu = tid >> 4;
            int u = u0 + uu;
            float gi = sigmoidf_(gsm[uu][0][b]);
            float gf = sigmoidf_(gsm[uu][1][b]);
            float gg = tanhf(gsm[uu][2][b]);
            float go = sigmoidf_(gsm[uu][3][b]);
            float c = gf * p.cr0[b * 512 + u] + gi * gg;
            crR = c;
            stA(p.hrb0 + b * 512 + u, go * tanhf(c));
        }
        ++tg; barArrive(p.slots, sidx, tg); gridWait(p.slots, tg);
    }

    for (int t = 0; t < TT; ++t) {
        const float* hrcur  = (t & 1) ? p.hrb1 : p.hrb0;
        float*       hrnext = (t & 1) ? p.hrb0 : p.hrb1;
        const float* hwprev = (t == 0) ? p.hw0 : (((t - 1) & 1) ? p.hwb1 : p.hwb0);
        float*       hwnext = (t & 1) ? p.hwb1 : p.hwb0;

        // ---- stage hr_t and hw_{t-1} into LDS via relaxed atomic word loads
        {
            #pragma unroll
            for (int q = 0; q < 8; ++q) {
                int idx = q * 1024 + tid * 4;
                float4 a4, b4;
                a4.x = ldA(hrcur + idx);     a4.y = ldA(hrcur + idx + 1);
                a4.z = ldA(hrcur + idx + 2); a4.w = ldA(hrcur + idx + 3);
                b4.x = ldA(hwprev + idx);     b4.y = ldA(hwprev + idx + 1);
                b4.z = ldA(hwprev + idx + 2); b4.w = ldA(hwprev + idx + 3);
                ((float4*)actH)[q * 256 + tid] = a4;
                ((float4*)actW)[q * 256 + tid] = b4;
            }
        }
        __syncthreads();

        // ========= stage A: deferred M update (local z) + sim + online partials
        {
            f8 h = ld8s(actH + bM * 512, lane);
            f8 w8 = {};
            if (t > 0) w8 = ld8s(actW + bM * 512, lane);
            float mx = -3.0e38f, ssum = 0.f;
            f8 macc = {};
            #pragma unroll
            for (int ii = 0; ii < 8; ++ii) {
                int rl = wv * 8 + ii;
                float4* mp0 = (float4*)&Mlds[rl][lane * 4];
                float4* mp1 = (float4*)&Mlds[rl][256 + lane * 4];
                f8 m; m.a = *mp0; m.b = *mp1;
                if (t > 0) {
                    float zf = 1.0f - __expf(simL[rl] - mxK) * sumInvK;
                    upd8(m, w8, zf);
                    *mp0 = m.a; *mp1 = m.b;
                }
                float s = wave_sum(dot8(m, h));
                float nmx = fmaxf(mx, s);
                float sc = __expf(mx - nmx);
                float wgt = __expf(s - nmx);
                fmaacc8(macc, sc, m, wgt);
                ssum = ssum * sc + wgt;
                mx = nmx;
                if (lane == 0) simL[rl] = s;
            }
            if (lane == 0) { smx4[wv] = mx; ssh4[wv] = ssum; }
            __syncthreads();
            float MXb = fmaxf(fmaxf(smx4[0], smx4[1]), fmaxf(smx4[2], smx4[3]));
            float sc2 = __expf(mx - MXb);
            float* d0 = &smacc[wv][lane * 4];
            float* d1 = &smacc[wv][256 + lane * 4];
            d0[0] = macc.a.x * sc2; d0[1] = macc.a.y * sc2;
            d0[2] = macc.a.z * sc2; d0[3] = macc.a.w * sc2;
            d1[0] = macc.b.x * sc2; d1[1] = macc.b.y * sc2;
            d1[2] = macc.b.z * sc2; d1[3] = macc.b.w * sc2;
            __syncthreads();
            for (int r = tid; r < 512; r += 256)
                stA(&p.mpart[(size_t)(kb * 8 + w2) * 512 + r],
                    smacc[0][r] + smacc[1][r] + smacc[2][r] + smacc[3][r]);
            if (tid == 0) {
                float sB = ssh4[0] * __expf(smx4[0] - MXb)
                         + ssh4[1] * __expf(smx4[1] - MXb)
                         + ssh4[2] * __expf(smx4[2] - MXb)
                         + ssh4[3] * __expf(smx4[3] - MXb);
                stA(&p.mxpart[kb * 8 + w2], MXb);
                stA(&p.sumpart[kb * 8 + w2], sB);
            }
        }
        // ========= stage A2: read-LSTM gates for t+1 (LDS activations)
        if (t < 63) {
            float gv0 = gatedotL(actH, wR0, lane);
            float gv1 = gatedotL(actH, wR1, lane);
            if ((lane & 3) == 0) {
                int b = (lane >> 2) & 15;
                gsm[0][wv][b] = gv0 + p.pre[(size_t)((t + 1) * 16 + b) * 2048 + jA];
                gsm[1][wv][b] = gv1 + p.pre[(size_t)((t + 1) * 16 + b) * 2048 + jA + 1];
            }
            __syncthreads();
            if (tid < 32) {
                int b = tid & 15, uu = tid >> 4;
                int u = u0 + uu;
                float gi = sigmoidf_(gsm[uu][0][b]);
                float gf = sigmoidf_(gsm[uu][1][b]);
                float gg = tanhf(gsm[uu][2][b]);
                float go = sigmoidf_(gsm[uu][3][b]);
                float c = gf * crR + gi * gg;
                crR = c;
                stA(hrnext + b * 512 + u, go * tanhf(c));
            }
        }

        // ========= stage B-lite: group (k,b) softmax stats + mbuf slice
        ++tg; barArrive(p.slots, sidx, tg); groupWait(p.slots, gbase, tg);
        {
            float mxp[8];
            #pragma unroll
            for (int w3 = 0; w3 < 8; ++w3) mxp[w3] = ldA(&p.mxpart[kb * 8 + w3]);
            float MX = -3.0e38f;
            #pragma unroll
            for (int w3 = 0; w3 < 8; ++w3) MX = fmaxf(MX, mxp[w3]);
            float SUM = 0.f;
            #pragma unroll
            for (int w3 = 0; w3 < 8; ++w3)
                SUM += ldA(&p.sumpart[kb * 8 + w3]) * __expf(mxp[w3] - MX);
            mxK = MX;
            sumInvK = 1.0f / SUM;
            if (tid < 64) {
                int r = w2 * 64 + tid;
                float acc = 0.f;
                #pragma unroll
                for (int w3 = 0; w3 < 8; ++w3)
                    acc += __expf(mxp[w3] - MX)
                         * ldA(&p.mpart[(size_t)(kb * 8 + w3) * 512 + r]);
                stA(&p.mbuf[(size_t)kb * 512 + r], acc * sumInvK);
            }
        }
        ++tg; barArrive(p.slots, sidx, tg); gridWait(p.slots, tg);

        // ========= stage C: comppre GEMV + hoisted vh = hw_prev . Whh_w
        float vh0, vh1;
        {
            vh0 = gatedotL(actW, wW0, lane);
            vh1 = gatedotL(actW, wW1, lane);
        }
        {
            float v;
            f8 A[16];
            if (part == 0) {
                v = gatedotL(actH, wC0, lane);
                ldactsA(A, p.mbuf, lane);
                v += gatedotR(A, wC1, lane);
            } else {
                ldactsA(A, p.mbuf + 16 * 512, lane);
                v = gatedotR(A, wC0, lane);
            }
            if ((lane & 3) == 0) {
                int b = (lane >> 2) & 15;
                cc[jj][part][b] = v;
            }
            __syncthreads();
            if (tid < 32) {
                int b = tid & 15, jj2 = tid >> 4;
                stA(&p.comppre[b * 512 + (u0 + jj2)],
                    cc[jj2][0][b] + cc[jj2][1][b] + bcsh[jj2]);
            }
        }
        ++tg; barArrive(p.slots, sidx, tg); gridWait(p.slots, tg);

        // ========= stage D: cooperative softmax -> E (coalesced, conflict-
        // free) in actH overlay; write-LSTM gates from LDS E
        {
            float v[8][4];
            #pragma unroll
            for (int k = 0; k < 8; ++k) {
                int idx = k * 1024 + tid * 4;
                #pragma unroll
                for (int j = 0; j < 4; ++j) v[k][j] = ldA(p.comppre + idx + j);
            }
            const int bpar = wv >> 1;     // tid>>7
            #pragma unroll
            for (int k = 0; k < 8; ++k) {
                float mk = fmaxf(fmaxf(v[k][0], v[k][1]), fmaxf(v[k][2], v[k][3]));
                mk = wave_max(mk);
                if (lane == 0) wmx[2 * k + bpar][wv & 1] = mk;
            }
            __syncthreads();                 // actH (hr) reads all done
            float4* Eld4 = (float4*)actH;
            #pragma unroll
            for (int k = 0; k < 8; ++k) {
                float mxb = fmaxf(wmx[2 * k + bpar][0], wmx[2 * k + bpar][1]);
                float e0 = __expf(v[k][0] - mxb), e1 = __expf(v[k][1] - mxb);
                float e2 = __expf(v[k][2] - mxb), e3 = __expf(v[k][3] - mxb);
                Eld4[k * 256 + tid] = make_float4(e0, e1, e2, e3);
                float sv = wave_sum(e0 + e1 + e2 + e3);
                if (lane == 0) wsm[2 * k + bpar][wv & 1] = sv;
            }
            __syncthreads();
            float ti0 = gatedotL(actH, wI0, lane);
            float ti1 = gatedotL(actH, wI1, lane);
            if ((lane & 3) == 0) {
                int bb = (lane >> 2) & 15;
                float siv = 1.0f / (wsm[bb][0] + wsm[bb][1]);
                gsm[0][wv][bb] = ti0 * siv + vh0 + bw0;
                gsm[1][wv][bb] = ti1 * siv + vh1 + bw1;
            }
            __syncthreads();
            if (tid < 32) {
                int bb = tid & 15, uu = tid >> 4;
                int u = u0 + uu;
                float gi = sigmoidf_(gsm[uu][0][bb]);
                float gf = sigmoidf_(gsm[uu][1][bb]);
                float gg = tanhf(gsm[uu][2][bb]);
                float go = sigmoidf_(gsm[uu][3][bb]);
                float c = gf * cwR + gi * gg;
                cwR = c;
                float h = go * tanhf(c);
                stA(hwnext + bb * 512 + u, h);
                p.outputs[(size_t)t * 8192 + bb * 512 + u] = h;
            }
        }
        ++tg; barArrive(p.slots, sidx, tg); gridWait(p.slots, tg);
    }

    // ---- epilogue: final deferred M update with (z_63, hw_63 = hwb1);
    //      write LDS M -> Mf; flush cr/cw registers to d_out
    {
        f8 w8 = ld8sA(p.hwb1 + (size_t)bM * 512, lane);
        #pragma unroll
        for (int ii = 0; ii < 8; ++ii) {
            int rl = wv * 8 + ii;
            float zf = 1.0f - __expf(simL[rl] - mxK) * sumInvK;
            f8 m;
            m.a = *(float4*)&Mlds[rl][lane * 4];
            m.b = *(float4*)&Mlds[rl][256 + lane * 4];
            upd8(m, w8, zf);
            st8s(p.Mw + (size_t)(rowG + rl) * 512, m, lane);
        }
        if (tid < 32) {
            int b = tid & 15, uu = tid >> 4;
            int u = u0 + uu;
            p.crS[b * 512 + u] = crR;
            p.cwS[b * 512 + u] = cwR;
        }
    }
}

extern "C" void kernel_launch(void* const* d_in, const int* in_sizes, int n_in,
                              void* d_out, int out_size, void* d_ws, size_t ws_size,
                              hipStream_t stream) {
    const float* emb   = (const float*)d_in[0];
    const float* hr0   = (const float*)d_in[1];
    const float* cr0   = (const float*)d_in[2];
    const float* hw0   = (const float*)d_in[3];
    const float* cw0   = (const float*)d_in[4];
    const float* io    = (const float*)d_in[5];
    const float* M0    = (const float*)d_in[6];
    const float* Wih_r = (const float*)d_in[7];
    const float* bih_r = (const float*)d_in[9];
    const float* bhh_r = (const float*)d_in[10];

    float* out = (float*)d_out;
    float* outputs = out;                    // [64][16][512]
    float* hrS1 = out + 524288;              // hr slot = hr parity-1 buf
    float* crS  = out + 532480;
    float* hwS1 = out + 540672;              // hw slot = hw parity-1 buf
    float* cwS  = out + 548864;
    float* Mw   = out + 557056;              // Mf (written once at epilogue)

    float* ws = (float*)d_ws;
    float* pre     = ws;                     // 1024*2048
    float* mbuf    = ws + 2097152;           // 32*512
    float* comppre = mbuf + 16384;           // 16*512
    float* hrB0    = comppre + 8192;         // hr parity 0
    float* hwB0    = hrB0 + 8192;            // hw parity 0
    float* mpart   = hwB0 + 8192;            // 256*512
    float* mxpart  = mpart + 131072;         // 256
    float* sumpart = mxpart + 256;           // 256
    unsigned* slots = (unsigned*)(sumpart + 256); // 256 uints

    (void)hipMemsetAsync(slots, 0, 256 * sizeof(unsigned), stream);

    k_pre<<<dim3(32, 16), 256, 0, stream>>>(emb, io, Wih_r, bih_r, bhh_r, pre);

    P p;
    p.pre = pre;
    p.Whh_r = (const float*)d_in[8];
    p.Wc    = (const float*)d_in[11];
    p.bc    = (const float*)d_in[12];
    p.Wih_w = (const float*)d_in[13];
    p.Whh_w = (const float*)d_in[14];
    p.bih_w = (const float*)d_in[15];
    p.bhh_w = (const float*)d_in[16];
    p.hr0 = hr0; p.cr0 = cr0; p.hw0 = hw0; p.cw0 = cw0; p.M0 = M0;
    p.mbuf = mbuf; p.comppre = comppre;
    p.mpart = mpart; p.mxpart = mxpart; p.sumpart = sumpart;
    p.hrb0 = hrB0; p.hrb1 = hrS1; p.crS = crS;
    p.hwb0 = hwB0; p.hwb1 = hwS1; p.cwS = cwS;
    p.outputs = outputs; p.Mw = Mw;
    p.slots = slots;

    k_persist<<<NBLK, 256, 0, stream>>>(p);
}